// Round 1
// baseline (885.802 us; speedup 1.0000x reference)
//
#include <hip/hip_runtime.h>

// ---------------------------------------------------------------------------
// GCN, bf16 pipeline, R7: XCD-pinned feature-chunked aggregation.
//  - All gathered bf16 feature tensors stored chunk-transposed [D/16][N][16]
//    (32 B rows). Sub-table per chunk = 3.2 MB < 4 MiB per-XCD L2.
//  - aggregate_c: gridDim.x = 8, chunk = blockIdx.x -> linear-id%8 XCD pinning
//    makes each chunk's gathers L2-resident (16x degree reuse captured).
//    D=256 done as two temporally-separated 8-chunk launches.
//  - Rows pre-scaled by dinv[src] at producers (same rounding count; kills
//    per-edge dinv loads, fmaf->add, self-loop = plain row add).
//  - esrc loads + aggregate output stores nontemporal (protect table residency).
//  - GEMMs (B-panel-in-LDS persistent MFMA) read A / write C chunked.
// ---------------------------------------------------------------------------

typedef __attribute__((ext_vector_type(8))) short bf16x8;
typedef __attribute__((ext_vector_type(4))) float f32x4;
typedef __attribute__((ext_vector_type(4))) unsigned uint4v;
typedef __attribute__((ext_vector_type(4))) float float4v;

__device__ __forceinline__ float bf_lo(unsigned u) {
    union { unsigned i; float f; } x; x.i = u << 16; return x.f;
}
__device__ __forceinline__ float bf_hi(unsigned u) {
    union { unsigned i; float f; } x; x.i = u & 0xFFFF0000u; return x.f;
}
__device__ __forceinline__ unsigned short f2bf(float f) {  // RNE
    union { float f; unsigned i; } x; x.f = f;
    unsigned r = x.i + 0x7FFFu + ((x.i >> 16) & 1u);
    return (unsigned short)(r >> 16);
}

// ----------------------------- CSR build -----------------------------------

__global__ __launch_bounds__(256) void count_edges(const int* __restrict__ col,
                                                   int E, int* __restrict__ cnt,
                                                   unsigned short* __restrict__ rank) {
    int base = (blockIdx.x * 256 + threadIdx.x) * 4;
    if (base + 3 < E) {
        int4 c = *(const int4*)(col + base);
        ushort4 r;
        r.x = (unsigned short)atomicAdd(&cnt[c.x], 1);
        r.y = (unsigned short)atomicAdd(&cnt[c.y], 1);
        r.z = (unsigned short)atomicAdd(&cnt[c.z], 1);
        r.w = (unsigned short)atomicAdd(&cnt[c.w], 1);
        *(ushort4*)(rank + base) = r;
    } else {
        for (int e = base; e < E; ++e)
            rank[e] = (unsigned short)atomicAdd(&cnt[col[e]], 1);
    }
}

__global__ __launch_bounds__(256) void scan_reduce(const int* __restrict__ cnt, int Nn,
                                                   int* __restrict__ blockSums) {
    __shared__ int s[256];
    int t = threadIdx.x;
    int base = blockIdx.x * 2048 + t * 8;
    int v = 0;
#pragma unroll
    for (int j = 0; j < 8; ++j) {
        int i = base + j;
        if (i < Nn) v += cnt[i];
    }
    s[t] = v;
    __syncthreads();
    for (int off = 128; off > 0; off >>= 1) {
        if (t < off) s[t] += s[t + off];
        __syncthreads();
    }
    if (t == 0) blockSums[blockIdx.x] = s[0];
}

__global__ __launch_bounds__(256) void scan_finish(const int* __restrict__ cnt, int Nn,
                                                   const int* __restrict__ blockSums, int nb,
                                                   int* __restrict__ offs,
                                                   float* __restrict__ dinv) {
    __shared__ int s[256];
    __shared__ int basePrefix;
    int t = threadIdx.x;
    if (t == 0) {
        int p = 0;
        for (int i = 0; i < (int)blockIdx.x; ++i) p += blockSums[i];
        basePrefix = p;
    }
    int base = blockIdx.x * 2048 + t * 8;
    int c[8];
    int sum = 0;
#pragma unroll
    for (int j = 0; j < 8; ++j) {
        int i = base + j;
        c[j] = (i < Nn) ? cnt[i] : 0;
        sum += c[j];
    }
    s[t] = sum;
    __syncthreads();
    for (int off = 1; off < 256; off <<= 1) {
        int v = (t >= off) ? s[t - off] : 0;
        __syncthreads();
        s[t] += v;
        __syncthreads();
    }
    int run = ((t > 0) ? s[t - 1] : 0) + basePrefix;
#pragma unroll
    for (int j = 0; j < 8; ++j) {
        int i = base + j;
        if (i < Nn) {
            offs[i] = run;
            dinv[i] = rsqrtf((float)(c[j] + 1));  // +1 self loop
            run += c[j];
        }
    }
    if (blockIdx.x == (unsigned)(nb - 1) && t == 255) offs[Nn] = basePrefix + s[255];
}

__global__ __launch_bounds__(256) void fill_csr(const int* __restrict__ row,
                                                const int* __restrict__ col,
                                                const unsigned short* __restrict__ rank,
                                                int E,
                                                const int* __restrict__ offs,
                                                int* __restrict__ esrc) {
    int base = (blockIdx.x * 256 + threadIdx.x) * 4;
    if (base + 3 < E) {
        int4 r = *(const int4*)(row + base);
        int4 c = *(const int4*)(col + base);
        ushort4 k = *(const ushort4*)(rank + base);
        esrc[offs[c.x] + k.x] = r.x;
        esrc[offs[c.y] + k.y] = r.y;
        esrc[offs[c.z] + k.z] = r.z;
        esrc[offs[c.w] + k.w] = r.w;
    } else {
        for (int e = base; e < E; ++e)
            esrc[offs[col[e]] + rank[e]] = row[e];
    }
}

// --------------------- fused converts (x + 3 weights) -----------------------
// xb written CHUNKED [8][N][16] and pre-scaled by dinv[node].

__global__ __launch_bounds__(256) void conv_fused(const float4* __restrict__ x4,
                                                  unsigned short* __restrict__ xb, int n4,
                                                  int Nn,
                                                  const float* __restrict__ dinv,
                                                  const float* __restrict__ W0,
                                                  const float* __restrict__ W1,
                                                  const float* __restrict__ W2,
                                                  unsigned short* __restrict__ Wt0,
                                                  unsigned short* __restrict__ Wt1,
                                                  unsigned short* __restrict__ Wt2) {
    int i = blockIdx.x * 256 + threadIdx.x;
    if (i < n4) {
        float4 v = x4[i];
        int node = i >> 5;        // 32 float4 per node
        int f0 = (i & 31) * 4;    // feature offset 0..124
        float dv = dinv[node];
        uint2 o;
        o.x = (unsigned)f2bf(v.x * dv) | ((unsigned)f2bf(v.y * dv) << 16);
        o.y = (unsigned)f2bf(v.z * dv) | ((unsigned)f2bf(v.w * dv) << 16);
        int ch = f0 >> 4;
        *(uint2*)(xb + (size_t)ch * Nn * 16 + (size_t)node * 16 + (f0 & 15)) = o;
        return;
    }
    int j = i - n4;
    if (j < 32768) {                        // Wt0[n*128+k] = W0[k*256+n]
        int n = j >> 7, k = j & 127;
        Wt0[j] = f2bf(W0[(size_t)k * 256 + n]);
    } else if (j < 32768 + 65536) {         // Wt1[n*256+k] = W1[k*256+n]
        int q = j - 32768;
        int n = q >> 8, k = q & 255;
        Wt1[q] = f2bf(W1[(size_t)k * 256 + n]);
    } else if (j < 32768 + 65536 + 32768) { // Wt2[n*256+k] = W2[k*128+n]
        int q = j - 98304;
        int n = q >> 8, k = q & 255;
        Wt2[q] = f2bf(W2[(size_t)k * 128 + n]);
    }
}

// ------------------- chunked, XCD-pinned aggregation ------------------------
// Table tb: [NCH][N][16] bf16 rows pre-scaled by dinv[src] (viewed as uints:
// [NCH][N][8]). grid = dim3(8, N/32); chunk = chunk0 + blockIdx.x -> with
// linear-id%8 round-robin, all blocks of chunk c run on XCD c; sub-table
// (3.2 MB) is L2-resident there.
// Wave: 8 nodes x 4 edge-groups x 2 lanes (16 B each).
// OUTBF: chunked bf16 out [NCH][N][16]; else dense fp32 [N][Dout] (+bias).
template<bool OUTBF, bool BIAS>
__global__ __launch_bounds__(256) void aggregate_c(const unsigned* __restrict__ tb,
                                                   const float* __restrict__ dinv,
                                                   const int* __restrict__ offs,
                                                   const int* __restrict__ esrc,
                                                   const float* __restrict__ bias,
                                                   void* __restrict__ out,
                                                   int Nn, int Dout, int chunk0) {
    int t = threadIdx.x;
    int lane = t & 63;
    int seg = lane >> 3;          // node within wave (0..7)
    int grp = (lane >> 1) & 3;    // edge group (0..3)
    int lid = lane & 1;           // 16-B half of the 32-B row
    int node = blockIdx.y * 32 + (t >> 6) * 8 + seg;
    if (node >= Nn) return;
    int chunk = chunk0 + (int)blockIdx.x;
    const unsigned* T = tb + (size_t)chunk * Nn * 8;

    float acc[8];
    if (grp == 0) {  // self loop: row already pre-scaled by dinv[node]
        uint4 u = *(const uint4*)(T + (size_t)node * 8 + lid * 4);
        const unsigned* up = (const unsigned*)&u;
#pragma unroll
        for (int q = 0; q < 4; ++q) {
            acc[2 * q]     = bf_lo(up[q]);
            acc[2 * q + 1] = bf_hi(up[q]);
        }
    } else {
#pragma unroll
        for (int q = 0; q < 8; ++q) acc[q] = 0.f;
    }

    int e0 = offs[node], e1 = offs[node + 1];
    int k = e0 + grp;
    int s = (k < e1) ? __builtin_nontemporal_load(esrc + k) : 0;
    while (k < e1) {
        int k2 = k + 4;
        int s2 = (k2 < e1) ? __builtin_nontemporal_load(esrc + k2) : 0;
        uint4 u = *(const uint4*)(T + (size_t)s * 8 + lid * 4);
        const unsigned* up = (const unsigned*)&u;
#pragma unroll
        for (int q = 0; q < 4; ++q) {
            acc[2 * q]     += bf_lo(up[q]);
            acc[2 * q + 1] += bf_hi(up[q]);
        }
        k = k2; s = s2;
    }

    // reduce over the 4 edge-groups (lane bits 1-2; stays inside 8-lane seg)
#pragma unroll
    for (int q = 0; q < 8; ++q) {
        acc[q] += __shfl_xor(acc[q], 2, 64);
        acc[q] += __shfl_xor(acc[q], 4, 64);
    }

    if (grp == 0) {
        float dc = dinv[node];
        if (OUTBF) {
            uint4v o;
#pragma unroll
            for (int q = 0; q < 4; ++q)
                o[q] = (unsigned)f2bf(acc[2 * q] * dc) |
                       ((unsigned)f2bf(acc[2 * q + 1] * dc) << 16);
            __builtin_nontemporal_store(
                o, (uint4v*)((unsigned*)out + (size_t)chunk * Nn * 8 +
                             (size_t)node * 8 + lid * 4));
        } else {
            float* ob = (float*)out + (size_t)node * Dout + chunk * 16 + lid * 8;
            float4v o0, o1;
#pragma unroll
            for (int q = 0; q < 4; ++q) {
                o0[q] = acc[q] * dc + (BIAS ? bias[chunk * 16 + lid * 8 + q] : 0.f);
                o1[q] = acc[4 + q] * dc + (BIAS ? bias[chunk * 16 + lid * 8 + 4 + q] : 0.f);
            }
            __builtin_nontemporal_store(o0, (float4v*)ob);
            __builtin_nontemporal_store(o1, (float4v*)(ob + 4));
        }
    }
}

// --------------------- MFMA GEMM: B panel in LDS, persistent M --------------
// A chunked [K/16][N][16]; C chunked [Dout/16][N][16]; Wt dense [Dout][K].
// Block: 4 waves (2x2), 128x128 tile, loops M (stride gridDim.y*128).
// Frag maps (verified): A/B: idx=lane&15, k=(lane>>4)*8+j;
//                       C: col=lane&15, row=(lane>>4)*4+reg.
// SCALE: multiply output row r by dinv[r] (producer pre-scale for gathers).
template<int K, bool RELU, bool BIAS, bool SCALE>
__global__ __launch_bounds__(256) void gemm_blds(const unsigned short* __restrict__ A,
                                                 const unsigned short* __restrict__ Wt,
                                                 const float* __restrict__ bias,
                                                 const float* __restrict__ dinv,
                                                 unsigned short* __restrict__ C,
                                                 int Nrows, int Dout) {
    constexpr int KP = K + 8;  // padded row stride (halves)
    __shared__ __align__(16) unsigned short Bsh[128 * KP];
    int t = threadIdx.x;
    int n0 = blockIdx.x << 7;

    constexpr int CHUNKS = 128 * (K / 8);
    for (int c = t; c < CHUNKS; c += 256) {
        int rown = c / (K / 8);
        int kc = c - rown * (K / 8);
        *(bf16x8*)&Bsh[rown * KP + kc * 8] =
            *(const bf16x8*)&Wt[(size_t)(n0 + rown) * K + kc * 8];
    }
    __syncthreads();

    int w = t >> 6, lane = t & 63;
    int lrow = lane & 15, lkq = lane >> 4;
    int wr = w >> 1, wc = w & 1;
    const unsigned short* bbase = &Bsh[(wc * 64 + lrow) * KP + lkq * 8];
    // chunked A addressing: element (r,k) at (k>>4)*N*16 + r*16 + (k&15);
    // fragment k = s*32 + lkq*8 + j  ->  chunk = 2s + (lkq>>1), within = (lkq&1)*8+j
    const size_t abase = (size_t)(lkq >> 1) * Nrows * 16 + (size_t)((lkq & 1) * 8);
    const size_t astep = (size_t)Nrows * 32;  // halves per K-32 step

    for (int m0 = blockIdx.y * 128; m0 < Nrows; m0 += gridDim.y * 128) {
        f32x4 acc[4][4];
#pragma unroll
        for (int i = 0; i < 4; ++i)
#pragma unroll
            for (int j = 0; j < 4; ++j) acc[i][j] = (f32x4){0.f, 0.f, 0.f, 0.f};

        const unsigned short* ap[4];
#pragma unroll
        for (int i = 0; i < 4; ++i) {
            int r = min(m0 + wr * 64 + i * 16 + lrow, Nrows - 1);
            ap[i] = A + abase + (size_t)r * 16;
        }

        bf16x8 a0[4], a1[4];
#pragma unroll
        for (int i = 0; i < 4; ++i) a0[i] = *(const bf16x8*)(ap[i]);
#pragma unroll
        for (int s = 0; s < K / 32; ++s) {
            bf16x8* cur = (s & 1) ? a1 : a0;
            bf16x8* nxt = (s & 1) ? a0 : a1;
            if (s + 1 < K / 32) {
#pragma unroll
                for (int i = 0; i < 4; ++i)
                    nxt[i] = *(const bf16x8*)(ap[i] + (size_t)(s + 1) * astep);
            }
            bf16x8 bfr[4];
#pragma unroll
            for (int j = 0; j < 4; ++j)
                bfr[j] = *(const bf16x8*)(bbase + j * 16 * KP + s * 32);
#pragma unroll
            for (int i = 0; i < 4; ++i)
#pragma unroll
                for (int j = 0; j < 4; ++j)
                    acc[i][j] = __builtin_amdgcn_mfma_f32_16x16x32_bf16(
                        cur[i], bfr[j], acc[i][j], 0, 0, 0);
        }

        float bj[4];
        unsigned short* cb[4];
#pragma unroll
        for (int j = 0; j < 4; ++j) {
            int colc = n0 + ((wc * 4 + j) << 4) + lrow;
            bj[j] = BIAS ? bias[colc] : 0.f;
            cb[j] = C + (size_t)(colc >> 4) * Nrows * 16 + (colc & 15);
        }
#pragma unroll
        for (int i = 0; i < 4; ++i) {
            int rb = m0 + wr * 64 + i * 16 + (lkq << 2);
#pragma unroll
            for (int r = 0; r < 4; ++r) {
                int rowc = rb + r;
                if (rowc < Nrows) {
                    float dv = SCALE ? dinv[rowc] : 1.f;
#pragma unroll
                    for (int j = 0; j < 4; ++j) {
                        float v = acc[i][j][r] + bj[j];
                        if (RELU) v = fmaxf(v, 0.f);
                        if (SCALE) v *= dv;
                        cb[j][(size_t)rowc * 16] = f2bf(v);
                    }
                }
            }
        }
    }
}

// ----------------------------- launch --------------------------------------

extern "C" void kernel_launch(void* const* d_in, const int* in_sizes, int n_in,
                              void* d_out, int out_size, void* d_ws, size_t ws_size,
                              hipStream_t stream) {
    const float* x  = (const float*)d_in[0];
    const int*   ei = (const int*)d_in[1];
    const float* W0 = (const float*)d_in[4];
    const float* b0 = (const float*)d_in[5];
    const float* W1 = (const float*)d_in[6];
    const float* b1 = (const float*)d_in[7];
    const float* W2 = (const float*)d_in[8];
    const float* b2 = (const float*)d_in[9];

    const int N = in_sizes[0] / 128;
    const int E = in_sizes[1] / 2;
    const int* row = ei;       // sources
    const int* col = ei + E;   // destinations

    char* wp = (char*)d_ws;
    auto carve = [&](size_t bytes) {
        void* p = (void*)wp;
        wp += (bytes + 255) & ~(size_t)255;
        return p;
    };
    const int NB = (N + 2047) / 2048;
    int*   cnt    = (int*)carve((size_t)N * 4);
    int*   offs   = (int*)carve((size_t)(N + 1) * 4);
    unsigned short* rank = (unsigned short*)carve((size_t)E * 2);
    int*   esrc   = (int*)carve((size_t)E * 4);
    float* dinv   = (float*)carve((size_t)N * 4);
    int*   bsums  = (int*)carve((size_t)NB * 4);
    unsigned short* Wt0 = (unsigned short*)carve((size_t)256 * 128 * 2);
    unsigned short* Wt1 = (unsigned short*)carve((size_t)256 * 256 * 2);
    unsigned short* Wt2 = (unsigned short*)carve((size_t)128 * 256 * 2);
    unsigned short* regX = (unsigned short*)carve((size_t)N * 256 * 2);
    unsigned short* xb    = regX;                    // [8][N][16] chunked, dinv-scaled
    unsigned short* agg0b = regX + (size_t)N * 128;  // [8][N][16] chunked
    unsigned short* h2b   = regX;                    // [16][N][16] (xb/agg0b dead)
    unsigned short* h1b = (unsigned short*)carve((size_t)N * 256 * 2);  // [16][N][16]
    unsigned short* hwb = h1b;                       // [8][N][16] (h1b dead by then)
    unsigned short* agg1b = (unsigned short*)carve((size_t)N * 256 * 2); // [16][N][16]

    // --- CSR build ---
    hipMemsetAsync(cnt, 0, (size_t)N * 4, stream);
    count_edges<<<(E / 4 + 255) / 256, 256, 0, stream>>>(col, E, cnt, rank);
    scan_reduce<<<NB, 256, 0, stream>>>(cnt, N, bsums);
    scan_finish<<<NB, 256, 0, stream>>>(cnt, N, bsums, NB, offs, dinv);
    fill_csr<<<(E / 4 + 255) / 256, 256, 0, stream>>>(row, col, rank, E, offs, esrc);

    // --- fused converts (needs dinv -> after scan_finish) ---
    {
        int n4 = N * 32;
        int tot = n4 + 32768 + 65536 + 32768;
        conv_fused<<<(tot + 255) / 256, 256, 0, stream>>>(
            (const float4*)x, xb, n4, N, dinv, W0, W1, W2, Wt0, Wt1, Wt2);
    }

    const int aggGY = (N + 31) / 32;  // 32 nodes / block

    // L0: agg0 = sum dinv-scaled xb ; h1b = relu(agg0 @ W0 + b0) * dinv
    aggregate_c<true, false><<<dim3(8, aggGY), 256, 0, stream>>>(
        (const unsigned*)xb, dinv, offs, esrc, nullptr, agg0b, N, 128, 0);
    gemm_blds<128, true, true, true><<<dim3(2, 391), 256, 0, stream>>>(
        agg0b, Wt0, b0, dinv, h1b, N, 256);
    // L1: agg1 = sum h1b ; two 8-chunk passes keep per-XCD WS at 3.2 MB
    aggregate_c<true, false><<<dim3(8, aggGY), 256, 0, stream>>>(
        (const unsigned*)h1b, dinv, offs, esrc, nullptr, agg1b, N, 256, 0);
    aggregate_c<true, false><<<dim3(8, aggGY), 256, 0, stream>>>(
        (const unsigned*)h1b, dinv, offs, esrc, nullptr, agg1b, N, 256, 8);
    gemm_blds<256, true, true, false><<<dim3(2, 256), 256, 0, stream>>>(
        agg1b, Wt1, b1, nullptr, h2b, N, 256);
    // L2: hwb = (h2 @ W2) * dinv ; out = sum hwb * dinv[dst] + b2 (fp32)
    gemm_blds<256, false, false, true><<<dim3(1, 391), 256, 0, stream>>>(
        h2b, Wt2, nullptr, dinv, hwb, N, 128);
    aggregate_c<false, true><<<dim3(8, aggGY), 256, 0, stream>>>(
        (const unsigned*)hwb, dinv, offs, esrc, b2, d_out, N, 128, 0);
}

// Round 2
// 820.912 us; speedup vs baseline: 1.0790x; 1.0790x over previous
//
#include <hip/hip_runtime.h>

// ---------------------------------------------------------------------------
// GCN, bf16 pipeline, R8: 64B-row feature chunks (32 feats), XCD-spread.
//  - Chunked tensors [D/32][N][32] bf16 -> 64B rows: every random gather
//    request is one fully-used 64B line (R7's 32B rows wasted half a line).
//  - D=256 agg: ONE dispatch, 8 chunks, chunk=bx -> one 6.4MB table per XCD
//    (mostly L2-resident, spill to L3 at >=R6 line rate).
//  - D=128 agg: 4 chunks x 2 destination halves across 8 XCDs.
//  - Wave = 2 nodes x 8 edge-groups x 4 lanes: 16 independent 64B line
//    requests per gather instruction.
//  - Rows pre-scaled by dinv[src] at producers (verified numerics).
//  - GEMMs read A / write C chunked-64B (dense 64B lines per lane-quad).
// ---------------------------------------------------------------------------

typedef __attribute__((ext_vector_type(8))) short bf16x8;
typedef __attribute__((ext_vector_type(4))) float f32x4;
typedef __attribute__((ext_vector_type(4))) unsigned uint4v;
typedef __attribute__((ext_vector_type(4))) float float4v;

__device__ __forceinline__ float bf_lo(unsigned u) {
    union { unsigned i; float f; } x; x.i = u << 16; return x.f;
}
__device__ __forceinline__ float bf_hi(unsigned u) {
    union { unsigned i; float f; } x; x.i = u & 0xFFFF0000u; return x.f;
}
__device__ __forceinline__ unsigned short f2bf(float f) {  // RNE
    union { float f; unsigned i; } x; x.f = f;
    unsigned r = x.i + 0x7FFFu + ((x.i >> 16) & 1u);
    return (unsigned short)(r >> 16);
}

// ----------------------------- CSR build -----------------------------------

__global__ __launch_bounds__(256) void count_edges(const int* __restrict__ col,
                                                   int E, int* __restrict__ cnt,
                                                   unsigned short* __restrict__ rank) {
    int base = (blockIdx.x * 256 + threadIdx.x) * 4;
    if (base + 3 < E) {
        int4 c = *(const int4*)(col + base);
        ushort4 r;
        r.x = (unsigned short)atomicAdd(&cnt[c.x], 1);
        r.y = (unsigned short)atomicAdd(&cnt[c.y], 1);
        r.z = (unsigned short)atomicAdd(&cnt[c.z], 1);
        r.w = (unsigned short)atomicAdd(&cnt[c.w], 1);
        *(ushort4*)(rank + base) = r;
    } else {
        for (int e = base; e < E; ++e)
            rank[e] = (unsigned short)atomicAdd(&cnt[col[e]], 1);
    }
}

__global__ __launch_bounds__(256) void scan_reduce(const int* __restrict__ cnt, int Nn,
                                                   int* __restrict__ blockSums) {
    __shared__ int s[256];
    int t = threadIdx.x;
    int base = blockIdx.x * 2048 + t * 8;
    int v = 0;
#pragma unroll
    for (int j = 0; j < 8; ++j) {
        int i = base + j;
        if (i < Nn) v += cnt[i];
    }
    s[t] = v;
    __syncthreads();
    for (int off = 128; off > 0; off >>= 1) {
        if (t < off) s[t] += s[t + off];
        __syncthreads();
    }
    if (t == 0) blockSums[blockIdx.x] = s[0];
}

__global__ __launch_bounds__(256) void scan_finish(const int* __restrict__ cnt, int Nn,
                                                   const int* __restrict__ blockSums, int nb,
                                                   int* __restrict__ offs,
                                                   float* __restrict__ dinv) {
    __shared__ int s[256];
    __shared__ int basePrefix;
    int t = threadIdx.x;
    if (t == 0) {
        int p = 0;
        for (int i = 0; i < (int)blockIdx.x; ++i) p += blockSums[i];
        basePrefix = p;
    }
    int base = blockIdx.x * 2048 + t * 8;
    int c[8];
    int sum = 0;
#pragma unroll
    for (int j = 0; j < 8; ++j) {
        int i = base + j;
        c[j] = (i < Nn) ? cnt[i] : 0;
        sum += c[j];
    }
    s[t] = sum;
    __syncthreads();
    for (int off = 1; off < 256; off <<= 1) {
        int v = (t >= off) ? s[t - off] : 0;
        __syncthreads();
        s[t] += v;
        __syncthreads();
    }
    int run = ((t > 0) ? s[t - 1] : 0) + basePrefix;
#pragma unroll
    for (int j = 0; j < 8; ++j) {
        int i = base + j;
        if (i < Nn) {
            offs[i] = run;
            dinv[i] = rsqrtf((float)(c[j] + 1));  // +1 self loop
            run += c[j];
        }
    }
    if (blockIdx.x == (unsigned)(nb - 1) && t == 255) offs[Nn] = basePrefix + s[255];
}

__global__ __launch_bounds__(256) void fill_csr(const int* __restrict__ row,
                                                const int* __restrict__ col,
                                                const unsigned short* __restrict__ rank,
                                                int E,
                                                const int* __restrict__ offs,
                                                int* __restrict__ esrc) {
    int base = (blockIdx.x * 256 + threadIdx.x) * 4;
    if (base + 3 < E) {
        int4 r = *(const int4*)(row + base);
        int4 c = *(const int4*)(col + base);
        ushort4 k = *(const ushort4*)(rank + base);
        esrc[offs[c.x] + k.x] = r.x;
        esrc[offs[c.y] + k.y] = r.y;
        esrc[offs[c.z] + k.z] = r.z;
        esrc[offs[c.w] + k.w] = r.w;
    } else {
        for (int e = base; e < E; ++e)
            esrc[offs[col[e]] + rank[e]] = row[e];
    }
}

// --------------------- fused converts (x + 3 weights) -----------------------
// xb written CHUNKED [4][N][32] and pre-scaled by dinv[node].

__global__ __launch_bounds__(256) void conv_fused(const float4* __restrict__ x4,
                                                  unsigned short* __restrict__ xb, int n4,
                                                  int Nn,
                                                  const float* __restrict__ dinv,
                                                  const float* __restrict__ W0,
                                                  const float* __restrict__ W1,
                                                  const float* __restrict__ W2,
                                                  unsigned short* __restrict__ Wt0,
                                                  unsigned short* __restrict__ Wt1,
                                                  unsigned short* __restrict__ Wt2) {
    int i = blockIdx.x * 256 + threadIdx.x;
    if (i < n4) {
        float4 v = x4[i];
        int node = i >> 5;        // 32 float4 per node
        int f0 = (i & 31) * 4;    // feature offset 0..124
        float dv = dinv[node];
        uint2 o;
        o.x = (unsigned)f2bf(v.x * dv) | ((unsigned)f2bf(v.y * dv) << 16);
        o.y = (unsigned)f2bf(v.z * dv) | ((unsigned)f2bf(v.w * dv) << 16);
        int ch = f0 >> 5;
        *(uint2*)(xb + (size_t)ch * Nn * 32 + (size_t)node * 32 + (f0 & 31)) = o;
        return;
    }
    int j = i - n4;
    if (j < 32768) {                        // Wt0[n*128+k] = W0[k*256+n]
        int n = j >> 7, k = j & 127;
        Wt0[j] = f2bf(W0[(size_t)k * 256 + n]);
    } else if (j < 32768 + 65536) {         // Wt1[n*256+k] = W1[k*256+n]
        int q = j - 32768;
        int n = q >> 8, k = q & 255;
        Wt1[q] = f2bf(W1[(size_t)k * 256 + n]);
    } else if (j < 32768 + 65536 + 32768) { // Wt2[n*256+k] = W2[k*128+n]
        int q = j - 98304;
        int n = q >> 8, k = q & 255;
        Wt2[q] = f2bf(W2[(size_t)k * 128 + n]);
    }
}

// ------------------- chunked 64B-row aggregation ----------------------------
// Table tb: [D/32][N][32] bf16 (uint view [.][N][16]), rows pre-scaled by
// dinv[src]. grid.x = 8: chunk = bx & cMask, destination-half = bx >> hShift.
// D=256: cMask=7,hShift=3 (1 chunk/XCD, all dests). D=128: cMask=3,hShift=2.
// Wave: 2 nodes x 8 edge-groups x 4 lanes (16B each -> full 64B row).
// OUTBF: chunked bf16 out; else dense fp32 [N][Dout] (+bias), *dinv[dst].
template<bool OUTBF, bool BIAS>
__global__ __launch_bounds__(256) void aggregate_c(const unsigned* __restrict__ tb,
                                                   const float* __restrict__ dinv,
                                                   const int* __restrict__ offs,
                                                   const int* __restrict__ esrc,
                                                   const float* __restrict__ bias,
                                                   void* __restrict__ out,
                                                   int Nn, int Dout,
                                                   int cMask, int hShift, int halfN) {
    int t = threadIdx.x;
    int lane = t & 63;
    int seg = lane >> 5;          // node within wave (0..1)
    int g   = (lane >> 2) & 7;    // edge group (0..7)
    int lid = lane & 3;           // 16B quarter of the 64B row
    int half = (int)blockIdx.x >> hShift;
    int node = half * halfN + blockIdx.y * 8 + (t >> 6) * 2 + seg;
    if (node >= Nn) return;
    int chunk = (int)blockIdx.x & cMask;
    const unsigned* T = tb + (size_t)chunk * Nn * 16;

    float acc[8];
    if (g == 0) {  // self loop: row already pre-scaled by dinv[node]
        uint4 u = *(const uint4*)(T + (size_t)node * 16 + lid * 4);
        const unsigned* up = (const unsigned*)&u;
#pragma unroll
        for (int q = 0; q < 4; ++q) {
            acc[2 * q]     = bf_lo(up[q]);
            acc[2 * q + 1] = bf_hi(up[q]);
        }
    } else {
#pragma unroll
        for (int q = 0; q < 8; ++q) acc[q] = 0.f;
    }

    int e0 = offs[node], e1 = offs[node + 1];
    int k = e0 + g;
    int s = (k < e1) ? __builtin_nontemporal_load(esrc + k) : 0;
    while (k < e1) {
        int k2 = k + 8;
        int s2 = (k2 < e1) ? __builtin_nontemporal_load(esrc + k2) : 0;
        uint4 u = *(const uint4*)(T + (size_t)s * 16 + lid * 4);
        const unsigned* up = (const unsigned*)&u;
#pragma unroll
        for (int q = 0; q < 4; ++q) {
            acc[2 * q]     += bf_lo(up[q]);
            acc[2 * q + 1] += bf_hi(up[q]);
        }
        k = k2; s = s2;
    }

    // reduce over the 8 edge-groups (lane bits 2-4; stays inside 32-lane seg)
#pragma unroll
    for (int q = 0; q < 8; ++q) {
        acc[q] += __shfl_xor(acc[q], 4, 64);
        acc[q] += __shfl_xor(acc[q], 8, 64);
        acc[q] += __shfl_xor(acc[q], 16, 64);
    }

    if (g == 0) {
        float dc = dinv[node];
        if (OUTBF) {
            uint4v o;
#pragma unroll
            for (int q = 0; q < 4; ++q)
                o[q] = (unsigned)f2bf(acc[2 * q] * dc) |
                       ((unsigned)f2bf(acc[2 * q + 1] * dc) << 16);
            __builtin_nontemporal_store(
                o, (uint4v*)((unsigned*)out + (size_t)chunk * Nn * 16 +
                             (size_t)node * 16 + lid * 4));
        } else {
            float* ob = (float*)out + (size_t)node * Dout + chunk * 32 + lid * 8;
            float4v o0, o1;
#pragma unroll
            for (int q = 0; q < 4; ++q) {
                o0[q] = acc[q] * dc + (BIAS ? bias[chunk * 32 + lid * 8 + q] : 0.f);
                o1[q] = acc[4 + q] * dc + (BIAS ? bias[chunk * 32 + lid * 8 + 4 + q] : 0.f);
            }
            __builtin_nontemporal_store(o0, (float4v*)ob);
            __builtin_nontemporal_store(o1, (float4v*)(ob + 4));
        }
    }
}

// --------------------- MFMA GEMM: B panel in LDS, persistent M --------------
// A chunked [K/32][N][32]; C chunked [Dout/32][N][32]; Wt dense [Dout][K].
// Block: 4 waves (2x2), 128x128 tile, loops M (stride gridDim.y*128).
// Frag maps (verified): A/B: idx=lane&15, k=(lane>>4)*8+j;
//                       C: col=lane&15, row=(lane>>4)*4+reg.
// Fragment k = s*32 + lkq*8 + j -> chunk s, row offset lkq*8+j (dense 64B
// rows per lane-quad). SCALE: multiply output row r by dinv[r].
template<int K, bool RELU, bool BIAS, bool SCALE>
__global__ __launch_bounds__(256) void gemm_blds(const unsigned short* __restrict__ A,
                                                 const unsigned short* __restrict__ Wt,
                                                 const float* __restrict__ bias,
                                                 const float* __restrict__ dinv,
                                                 unsigned short* __restrict__ C,
                                                 int Nrows, int Dout) {
    constexpr int KP = K + 8;  // padded row stride (halves)
    __shared__ __align__(16) unsigned short Bsh[128 * KP];
    int t = threadIdx.x;
    int n0 = blockIdx.x << 7;

    constexpr int CHUNKS = 128 * (K / 8);
    for (int c = t; c < CHUNKS; c += 256) {
        int rown = c / (K / 8);
        int kc = c - rown * (K / 8);
        *(bf16x8*)&Bsh[rown * KP + kc * 8] =
            *(const bf16x8*)&Wt[(size_t)(n0 + rown) * K + kc * 8];
    }
    __syncthreads();

    int w = t >> 6, lane = t & 63;
    int lrow = lane & 15, lkq = lane >> 4;
    int wr = w >> 1, wc = w & 1;
    const unsigned short* bbase = &Bsh[(wc * 64 + lrow) * KP + lkq * 8];
    const size_t astep = (size_t)Nrows * 32;  // halves per K-32 step (chunk)

    for (int m0 = blockIdx.y * 128; m0 < Nrows; m0 += gridDim.y * 128) {
        f32x4 acc[4][4];
#pragma unroll
        for (int i = 0; i < 4; ++i)
#pragma unroll
            for (int j = 0; j < 4; ++j) acc[i][j] = (f32x4){0.f, 0.f, 0.f, 0.f};

        const unsigned short* ap[4];
#pragma unroll
        for (int i = 0; i < 4; ++i) {
            int r = min(m0 + wr * 64 + i * 16 + lrow, Nrows - 1);
            ap[i] = A + (size_t)r * 32 + lkq * 8;
        }

        bf16x8 a0[4], a1[4];
#pragma unroll
        for (int i = 0; i < 4; ++i) a0[i] = *(const bf16x8*)(ap[i]);
#pragma unroll
        for (int s = 0; s < K / 32; ++s) {
            bf16x8* cur = (s & 1) ? a1 : a0;
            bf16x8* nxt = (s & 1) ? a0 : a1;
            if (s + 1 < K / 32) {
#pragma unroll
                for (int i = 0; i < 4; ++i)
                    nxt[i] = *(const bf16x8*)(ap[i] + (size_t)(s + 1) * astep);
            }
            bf16x8 bfr[4];
#pragma unroll
            for (int j = 0; j < 4; ++j)
                bfr[j] = *(const bf16x8*)(bbase + j * 16 * KP + s * 32);
#pragma unroll
            for (int i = 0; i < 4; ++i)
#pragma unroll
                for (int j = 0; j < 4; ++j)
                    acc[i][j] = __builtin_amdgcn_mfma_f32_16x16x32_bf16(
                        cur[i], bfr[j], acc[i][j], 0, 0, 0);
        }

        float bj[4];
        unsigned short* cb[4];
#pragma unroll
        for (int j = 0; j < 4; ++j) {
            int colc = n0 + ((wc * 4 + j) << 4) + lrow;
            bj[j] = BIAS ? bias[colc] : 0.f;
            cb[j] = C + (size_t)(colc >> 5) * Nrows * 32 + (colc & 31);
        }
#pragma unroll
        for (int i = 0; i < 4; ++i) {
            int rb = m0 + wr * 64 + i * 16 + (lkq << 2);
#pragma unroll
            for (int r = 0; r < 4; ++r) {
                int rowc = rb + r;
                if (rowc < Nrows) {
                    float dv = SCALE ? dinv[rowc] : 1.f;
#pragma unroll
                    for (int j = 0; j < 4; ++j) {
                        float v = acc[i][j][r] + bj[j];
                        if (RELU) v = fmaxf(v, 0.f);
                        if (SCALE) v *= dv;
                        cb[j][(size_t)rowc * 32] = f2bf(v);
                    }
                }
            }
        }
    }
}

// ----------------------------- launch --------------------------------------

extern "C" void kernel_launch(void* const* d_in, const int* in_sizes, int n_in,
                              void* d_out, int out_size, void* d_ws, size_t ws_size,
                              hipStream_t stream) {
    const float* x  = (const float*)d_in[0];
    const int*   ei = (const int*)d_in[1];
    const float* W0 = (const float*)d_in[4];
    const float* b0 = (const float*)d_in[5];
    const float* W1 = (const float*)d_in[6];
    const float* b1 = (const float*)d_in[7];
    const float* W2 = (const float*)d_in[8];
    const float* b2 = (const float*)d_in[9];

    const int N = in_sizes[0] / 128;
    const int E = in_sizes[1] / 2;
    const int* row = ei;       // sources
    const int* col = ei + E;   // destinations

    char* wp = (char*)d_ws;
    auto carve = [&](size_t bytes) {
        void* p = (void*)wp;
        wp += (bytes + 255) & ~(size_t)255;
        return p;
    };
    const int NB = (N + 2047) / 2048;
    int*   cnt    = (int*)carve((size_t)N * 4);
    int*   offs   = (int*)carve((size_t)(N + 1) * 4);
    unsigned short* rank = (unsigned short*)carve((size_t)E * 2);
    int*   esrc   = (int*)carve((size_t)E * 4);
    float* dinv   = (float*)carve((size_t)N * 4);
    int*   bsums  = (int*)carve((size_t)NB * 4);
    unsigned short* Wt0 = (unsigned short*)carve((size_t)256 * 128 * 2);
    unsigned short* Wt1 = (unsigned short*)carve((size_t)256 * 256 * 2);
    unsigned short* Wt2 = (unsigned short*)carve((size_t)128 * 256 * 2);
    unsigned short* regX = (unsigned short*)carve((size_t)N * 256 * 2);
    unsigned short* xb    = regX;                    // [4][N][32] chunked, dinv-scaled
    unsigned short* agg0b = regX + (size_t)N * 128;  // [4][N][32] chunked
    unsigned short* h2b   = regX;                    // [8][N][32] (xb/agg0b dead)
    unsigned short* h1b = (unsigned short*)carve((size_t)N * 256 * 2);  // [8][N][32]
    unsigned short* hwb = h1b;                       // [4][N][32] (h1b dead by then)
    unsigned short* agg1b = (unsigned short*)carve((size_t)N * 256 * 2); // [8][N][32]

    // --- CSR build ---
    hipMemsetAsync(cnt, 0, (size_t)N * 4, stream);
    count_edges<<<(E / 4 + 255) / 256, 256, 0, stream>>>(col, E, cnt, rank);
    scan_reduce<<<NB, 256, 0, stream>>>(cnt, N, bsums);
    scan_finish<<<NB, 256, 0, stream>>>(cnt, N, bsums, NB, offs, dinv);
    fill_csr<<<(E / 4 + 255) / 256, 256, 0, stream>>>(row, col, rank, E, offs, esrc);

    // --- fused converts (needs dinv -> after scan_finish) ---
    {
        int n4 = N * 32;
        int tot = n4 + 32768 + 65536 + 32768;
        conv_fused<<<(tot + 255) / 256, 256, 0, stream>>>(
            (const float4*)x, xb, n4, N, dinv, W0, W1, W2, Wt0, Wt1, Wt2);
    }

    // D=128 aggs: 4 chunks x 2 dest-halves; D=256: 8 chunks, all dests.
    const int halfN = (((N + 1) >> 1) + 7) & ~7;   // multiple of 8
    const int gyHalf = halfN / 8;
    const int gyFull = (N + 7) / 8;

    // L0: agg0 = sum dinv-scaled xb ; h1b = relu(agg0 @ W0 + b0) * dinv
    aggregate_c<true, false><<<dim3(8, gyHalf), 256, 0, stream>>>(
        (const unsigned*)xb, dinv, offs, esrc, nullptr, agg0b, N, 128, 3, 2, halfN);
    gemm_blds<128, true, true, true><<<dim3(2, 391), 256, 0, stream>>>(
        agg0b, Wt0, b0, dinv, h1b, N, 256);
    // L1: agg1 = sum h1b (one dispatch, 8 chunks) ; h2 = relu(agg1 @ W1 + b1)
    aggregate_c<true, false><<<dim3(8, gyFull), 256, 0, stream>>>(
        (const unsigned*)h1b, dinv, offs, esrc, nullptr, agg1b, N, 256, 7, 3, N);
    gemm_blds<256, true, true, false><<<dim3(2, 256), 256, 0, stream>>>(
        agg1b, Wt1, b1, nullptr, h2b, N, 256);
    // L2: hwb = (h2 @ W2) * dinv ; out = sum hwb * dinv[dst] + b2 (fp32)
    gemm_blds<256, false, false, true><<<dim3(1, 391), 256, 0, stream>>>(
        h2b, Wt2, nullptr, dinv, hwb, N, 128);
    aggregate_c<false, true><<<dim3(8, gyHalf), 256, 0, stream>>>(
        (const unsigned*)hwb, dinv, offs, esrc, b2, d_out, N, 128, 3, 2, halfN);
}

// Round 3
// 649.838 us; speedup vs baseline: 1.3631x; 1.2633x over previous
//
#include <hip/hip_runtime.h>

// ---------------------------------------------------------------------------
// GCN, bf16 pipeline, R9 = R6 (proven 592us) + producer dinv pre-scaling.
//  - R7/R8 chunking falsified: L2-hit random path caps at ~6 TB/s line-touched,
//    no better than the dense ~3.35 TB/s L2-miss path; small rows waste lines.
//    Dense [N][D] rows + 1 node/wave (R6) is the empirical best per agg (124us).
//  - NEW vs R6: all gathered tables are pre-scaled by dinv[src] at producers
//    (conv for xb, GEMM epilogue for h1b/hwb). Removes the per-edge dinv
//    random load + shortens dependent chain; fma -> add. Numerics validated
//    in R7/R8 (absmax identical).
// ---------------------------------------------------------------------------

typedef __attribute__((ext_vector_type(8))) short bf16x8;
typedef __attribute__((ext_vector_type(4))) float f32x4;

__device__ __forceinline__ float bf_lo(unsigned u) {
    union { unsigned i; float f; } x; x.i = u << 16; return x.f;
}
__device__ __forceinline__ float bf_hi(unsigned u) {
    union { unsigned i; float f; } x; x.i = u & 0xFFFF0000u; return x.f;
}
__device__ __forceinline__ unsigned short f2bf(float f) {  // RNE
    union { float f; unsigned i; } x; x.f = f;
    unsigned r = x.i + 0x7FFFu + ((x.i >> 16) & 1u);
    return (unsigned short)(r >> 16);
}

// ----------------------------- CSR build -----------------------------------

__global__ __launch_bounds__(256) void count_edges(const int* __restrict__ col,
                                                   int E, int* __restrict__ cnt,
                                                   unsigned short* __restrict__ rank) {
    int base = (blockIdx.x * 256 + threadIdx.x) * 4;
    if (base + 3 < E) {
        int4 c = *(const int4*)(col + base);
        ushort4 r;
        r.x = (unsigned short)atomicAdd(&cnt[c.x], 1);
        r.y = (unsigned short)atomicAdd(&cnt[c.y], 1);
        r.z = (unsigned short)atomicAdd(&cnt[c.z], 1);
        r.w = (unsigned short)atomicAdd(&cnt[c.w], 1);
        *(ushort4*)(rank + base) = r;
    } else {
        for (int e = base; e < E; ++e)
            rank[e] = (unsigned short)atomicAdd(&cnt[col[e]], 1);
    }
}

__global__ __launch_bounds__(256) void scan_reduce(const int* __restrict__ cnt, int Nn,
                                                   int* __restrict__ blockSums) {
    __shared__ int s[256];
    int t = threadIdx.x;
    int base = blockIdx.x * 2048 + t * 8;
    int v = 0;
#pragma unroll
    for (int j = 0; j < 8; ++j) {
        int i = base + j;
        if (i < Nn) v += cnt[i];
    }
    s[t] = v;
    __syncthreads();
    for (int off = 128; off > 0; off >>= 1) {
        if (t < off) s[t] += s[t + off];
        __syncthreads();
    }
    if (t == 0) blockSums[blockIdx.x] = s[0];
}

__global__ __launch_bounds__(256) void scan_finish(const int* __restrict__ cnt, int Nn,
                                                   const int* __restrict__ blockSums, int nb,
                                                   int* __restrict__ offs,
                                                   float* __restrict__ dinv) {
    __shared__ int s[256];
    __shared__ int basePrefix;
    int t = threadIdx.x;
    if (t == 0) {
        int p = 0;
        for (int i = 0; i < (int)blockIdx.x; ++i) p += blockSums[i];
        basePrefix = p;
    }
    int base = blockIdx.x * 2048 + t * 8;
    int c[8];
    int sum = 0;
#pragma unroll
    for (int j = 0; j < 8; ++j) {
        int i = base + j;
        c[j] = (i < Nn) ? cnt[i] : 0;
        sum += c[j];
    }
    s[t] = sum;
    __syncthreads();
    for (int off = 1; off < 256; off <<= 1) {
        int v = (t >= off) ? s[t - off] : 0;
        __syncthreads();
        s[t] += v;
        __syncthreads();
    }
    int run = ((t > 0) ? s[t - 1] : 0) + basePrefix;
#pragma unroll
    for (int j = 0; j < 8; ++j) {
        int i = base + j;
        if (i < Nn) {
            offs[i] = run;
            dinv[i] = rsqrtf((float)(c[j] + 1));  // +1 self loop
            run += c[j];
        }
    }
    if (blockIdx.x == (unsigned)(nb - 1) && t == 255) offs[Nn] = basePrefix + s[255];
}

__global__ __launch_bounds__(256) void fill_csr(const int* __restrict__ row,
                                                const int* __restrict__ col,
                                                const unsigned short* __restrict__ rank,
                                                int E,
                                                const int* __restrict__ offs,
                                                int* __restrict__ esrc) {
    int base = (blockIdx.x * 256 + threadIdx.x) * 4;
    if (base + 3 < E) {
        int4 r = *(const int4*)(row + base);
        int4 c = *(const int4*)(col + base);
        ushort4 k = *(const ushort4*)(rank + base);
        esrc[offs[c.x] + k.x] = r.x;
        esrc[offs[c.y] + k.y] = r.y;
        esrc[offs[c.z] + k.z] = r.z;
        esrc[offs[c.w] + k.w] = r.w;
    } else {
        for (int e = base; e < E; ++e)
            esrc[offs[col[e]] + rank[e]] = row[e];
    }
}

// --------------------- fused converts (x + 3 weights) -----------------------
// xb dense [N][128] bf16, pre-scaled by dinv[node].

__global__ __launch_bounds__(256) void conv_fused(const float4* __restrict__ x4,
                                                  uint2* __restrict__ xb, int n4,
                                                  const float* __restrict__ dinv,
                                                  const float* __restrict__ W0,
                                                  const float* __restrict__ W1,
                                                  const float* __restrict__ W2,
                                                  unsigned short* __restrict__ Wt0,
                                                  unsigned short* __restrict__ Wt1,
                                                  unsigned short* __restrict__ Wt2) {
    int i = blockIdx.x * 256 + threadIdx.x;
    if (i < n4) {
        float4 v = x4[i];
        float dv = dinv[i >> 5];   // 32 float4 per node (D=128)
        uint2 o;
        o.x = (unsigned)f2bf(v.x * dv) | ((unsigned)f2bf(v.y * dv) << 16);
        o.y = (unsigned)f2bf(v.z * dv) | ((unsigned)f2bf(v.w * dv) << 16);
        xb[i] = o;
        return;
    }
    int j = i - n4;
    if (j < 32768) {                        // Wt0[n*128+k] = W0[k*256+n]
        int n = j >> 7, k = j & 127;
        Wt0[j] = f2bf(W0[(size_t)k * 256 + n]);
    } else if (j < 32768 + 65536) {         // Wt1[n*256+k] = W1[k*256+n]
        int q = j - 32768;
        int n = q >> 8, k = q & 255;
        Wt1[q] = f2bf(W1[(size_t)k * 256 + n]);
    } else if (j < 32768 + 65536 + 32768) { // Wt2[n*256+k] = W2[k*128+n]
        int q = j - 98304;
        int n = q >> 8, k = q & 255;
        Wt2[q] = f2bf(W2[(size_t)k * 128 + n]);
    }
}

// ----------------------------- aggregation (R6 structure) -------------------
// Table hb: dense [N][DFEAT] bf16 rows PRE-SCALED by dinv[src].
// Wave = 1 node; G edges in parallel (128->4, 256->2), L lanes/row, 16B/lane.
// out[node] = dinv[node]*(sum_nbr row + row[node]) (+bias, fp32 if !OUTBF).
template<int DFEAT, bool OUTBF, bool BIAS>
__global__ __launch_bounds__(256) void aggregate_g(const unsigned* __restrict__ hb,
                                                   const float* __restrict__ dinv,
                                                   const int* __restrict__ offs,
                                                   const int* __restrict__ esrc,
                                                   const float* __restrict__ bias,
                                                   void* __restrict__ out, int Nn) {
    constexpr int RW = DFEAT / 2;    // uints per row
    constexpr int G  = 512 / DFEAT;  // parallel edges (128->4, 256->2)
    constexpr int L  = 64 / G;       // lanes per row
    int node = (int)((blockIdx.x * 256u + threadIdx.x) >> 6);
    if (node >= Nn) return;
    int lane = threadIdx.x & 63;
    int grp = lane / L;
    int lid = lane % L;

    float acc[8];
    if (grp == 0) {  // self-loop term (row pre-scaled by dinv[node])
        uint4 u = *(const uint4*)(hb + (size_t)node * RW + lid * 4);
        const unsigned* up = (const unsigned*)&u;
#pragma unroll
        for (int q = 0; q < 4; ++q) {
            acc[2 * q]     = bf_lo(up[q]);
            acc[2 * q + 1] = bf_hi(up[q]);
        }
    } else {
#pragma unroll
        for (int q = 0; q < 8; ++q) acc[q] = 0.f;
    }

    int e0 = offs[node], e1 = offs[node + 1];
    int k = e0 + grp;
    while (k + 3 * G < e1) {
        int s0 = __builtin_nontemporal_load(esrc + k);
        int s1 = __builtin_nontemporal_load(esrc + k + G);
        int s2 = __builtin_nontemporal_load(esrc + k + 2 * G);
        int s3 = __builtin_nontemporal_load(esrc + k + 3 * G);
        uint4 u0 = *(const uint4*)(hb + (size_t)s0 * RW + lid * 4);
        uint4 u1 = *(const uint4*)(hb + (size_t)s1 * RW + lid * 4);
        uint4 u2 = *(const uint4*)(hb + (size_t)s2 * RW + lid * 4);
        uint4 u3 = *(const uint4*)(hb + (size_t)s3 * RW + lid * 4);
        const unsigned* u0p = (const unsigned*)&u0;
        const unsigned* u1p = (const unsigned*)&u1;
        const unsigned* u2p = (const unsigned*)&u2;
        const unsigned* u3p = (const unsigned*)&u3;
#pragma unroll
        for (int q = 0; q < 4; ++q) {
            acc[2 * q]     += bf_lo(u0p[q]) + bf_lo(u1p[q]);
            acc[2 * q + 1] += bf_hi(u0p[q]) + bf_hi(u1p[q]);
            acc[2 * q]     += bf_lo(u2p[q]) + bf_lo(u3p[q]);
            acc[2 * q + 1] += bf_hi(u2p[q]) + bf_hi(u3p[q]);
        }
        k += 4 * G;
    }
    while (k < e1) {
        int s0 = __builtin_nontemporal_load(esrc + k);
        uint4 u0 = *(const uint4*)(hb + (size_t)s0 * RW + lid * 4);
        const unsigned* u0p = (const unsigned*)&u0;
#pragma unroll
        for (int q = 0; q < 4; ++q) {
            acc[2 * q]     += bf_lo(u0p[q]);
            acc[2 * q + 1] += bf_hi(u0p[q]);
        }
        k += G;
    }

#pragma unroll
    for (int q = 0; q < 8; ++q) {
        if (G == 4) {
            acc[q] += __shfl_xor(acc[q], 16, 64);
            acc[q] += __shfl_xor(acc[q], 32, 64);
        } else {
            acc[q] += __shfl_xor(acc[q], 32, 64);
        }
    }

    float dc = dinv[node];
    if (grp == 0) {
        if (OUTBF) {
            uint4 o;
            unsigned* op = (unsigned*)&o;
#pragma unroll
            for (int q = 0; q < 4; ++q) {
                float v0 = acc[2 * q] * dc;
                float v1 = acc[2 * q + 1] * dc;
                op[q] = (unsigned)f2bf(v0) | ((unsigned)f2bf(v1) << 16);
            }
            *(uint4*)((unsigned*)out + (size_t)node * RW + lid * 4) = o;
        } else {
            float4 o0, o1;
            float* o0p = (float*)&o0;
            float* o1p = (float*)&o1;
#pragma unroll
            for (int q = 0; q < 4; ++q) {
                float b0v = BIAS ? bias[lid * 8 + 2 * q] : 0.f;
                float b1v = BIAS ? bias[lid * 8 + 2 * q + 1] : 0.f;
                float v0 = acc[2 * q] * dc + b0v;
                float v1 = acc[2 * q + 1] * dc + b1v;
                if (q < 2) { o0p[2 * q] = v0; o0p[2 * q + 1] = v1; }
                else       { o1p[2 * (q - 2)] = v0; o1p[2 * (q - 2) + 1] = v1; }
            }
            float* ob = (float*)out + (size_t)node * DFEAT + lid * 8;
            *(float4*)ob = o0;
            *(float4*)(ob + 4) = o1;
        }
    }
}

// --------------------- MFMA GEMM: B panel in LDS, persistent M --------------
// C[Nrows,Dout] = A[Nrows,K]@W (+bias)(+relu)(*dinv[row]); A,Wt,C bf16 dense.
// Block: 4 waves (2x2), 128x128 tile, loops M-tiles (stride gridDim.y*128).
// Frag maps (verified R3-R6): A/B: idx=lane&15, k=(lane>>4)*8+j;
//                             C: col=lane&15, row=(lane>>4)*4+reg.
template<int K, bool RELU, bool BIAS, bool SCALE>
__global__ __launch_bounds__(256) void gemm_blds(const unsigned short* __restrict__ A,
                                                 const unsigned short* __restrict__ Wt,
                                                 const float* __restrict__ bias,
                                                 const float* __restrict__ dinv,
                                                 unsigned short* __restrict__ C,
                                                 int Nrows, int Dout) {
    constexpr int KP = K + 8;  // padded row stride (halves)
    __shared__ __align__(16) unsigned short Bsh[128 * KP];
    int t = threadIdx.x;
    int n0 = blockIdx.x << 7;

    constexpr int CHUNKS = 128 * (K / 8);
    for (int c = t; c < CHUNKS; c += 256) {
        int rown = c / (K / 8);
        int kc = c - rown * (K / 8);
        *(bf16x8*)&Bsh[rown * KP + kc * 8] =
            *(const bf16x8*)&Wt[(size_t)(n0 + rown) * K + kc * 8];
    }
    __syncthreads();

    int w = t >> 6, lane = t & 63;
    int lrow = lane & 15, lkq = lane >> 4;
    int wr = w >> 1, wc = w & 1;
    const unsigned short* bbase = &Bsh[(wc * 64 + lrow) * KP + lkq * 8];

    for (int m0 = blockIdx.y * 128; m0 < Nrows; m0 += gridDim.y * 128) {
        f32x4 acc[4][4];
#pragma unroll
        for (int i = 0; i < 4; ++i)
#pragma unroll
            for (int j = 0; j < 4; ++j) acc[i][j] = (f32x4){0.f, 0.f, 0.f, 0.f};

        const unsigned short* ap[4];
#pragma unroll
        for (int i = 0; i < 4; ++i) {
            int r = min(m0 + wr * 64 + i * 16 + lrow, Nrows - 1);
            ap[i] = A + (size_t)r * K + lkq * 8;
        }

        bf16x8 a0[4], a1[4];
#pragma unroll
        for (int i = 0; i < 4; ++i) a0[i] = *(const bf16x8*)(ap[i]);
#pragma unroll
        for (int s = 0; s < K / 32; ++s) {
            bf16x8* cur = (s & 1) ? a1 : a0;
            bf16x8* nxt = (s & 1) ? a0 : a1;
            if (s + 1 < K / 32) {
#pragma unroll
                for (int i = 0; i < 4; ++i)
                    nxt[i] = *(const bf16x8*)(ap[i] + (s + 1) * 32);
            }
            bf16x8 bfr[4];
#pragma unroll
            for (int j = 0; j < 4; ++j)
                bfr[j] = *(const bf16x8*)(bbase + j * 16 * KP + s * 32);
#pragma unroll
            for (int i = 0; i < 4; ++i)
#pragma unroll
                for (int j = 0; j < 4; ++j)
                    acc[i][j] = __builtin_amdgcn_mfma_f32_16x16x32_bf16(
                        cur[i], bfr[j], acc[i][j], 0, 0, 0);
        }

#pragma unroll
        for (int j = 0; j < 4; ++j) {
            int colc = n0 + ((wc * 4 + j) << 4) + lrow;
            float bj = BIAS ? bias[colc] : 0.f;
#pragma unroll
            for (int i = 0; i < 4; ++i) {
                int rb = m0 + wr * 64 + i * 16 + (lkq << 2);
                f32x4 c = acc[i][j];
#pragma unroll
                for (int r = 0; r < 4; ++r) {
                    int rowc = rb + r;
                    if (rowc < Nrows) {
                        float v = c[r] + bj;
                        if (RELU) v = fmaxf(v, 0.f);
                        if (SCALE) v *= dinv[rowc];
                        C[(size_t)rowc * Dout + colc] = f2bf(v);
                    }
                }
            }
        }
    }
}

// ----------------------------- launch --------------------------------------

extern "C" void kernel_launch(void* const* d_in, const int* in_sizes, int n_in,
                              void* d_out, int out_size, void* d_ws, size_t ws_size,
                              hipStream_t stream) {
    const float* x  = (const float*)d_in[0];
    const int*   ei = (const int*)d_in[1];
    const float* W0 = (const float*)d_in[4];
    const float* b0 = (const float*)d_in[5];
    const float* W1 = (const float*)d_in[6];
    const float* b1 = (const float*)d_in[7];
    const float* W2 = (const float*)d_in[8];
    const float* b2 = (const float*)d_in[9];

    const int N = in_sizes[0] / 128;
    const int E = in_sizes[1] / 2;
    const int* row = ei;       // sources
    const int* col = ei + E;   // destinations

    char* wp = (char*)d_ws;
    auto carve = [&](size_t bytes) {
        void* p = (void*)wp;
        wp += (bytes + 255) & ~(size_t)255;
        return p;
    };
    const int NB = (N + 2047) / 2048;
    int*   cnt    = (int*)carve((size_t)N * 4);
    int*   offs   = (int*)carve((size_t)(N + 1) * 4);
    unsigned short* rank = (unsigned short*)carve((size_t)E * 2);
    int*   esrc   = (int*)carve((size_t)E * 4);
    float* dinv   = (float*)carve((size_t)N * 4);
    int*   bsums  = (int*)carve((size_t)NB * 4);
    unsigned short* Wt0 = (unsigned short*)carve((size_t)256 * 128 * 2);
    unsigned short* Wt1 = (unsigned short*)carve((size_t)256 * 256 * 2);
    unsigned short* Wt2 = (unsigned short*)carve((size_t)128 * 256 * 2);
    unsigned short* regX = (unsigned short*)carve((size_t)N * 256 * 2);
    unsigned short* xb    = regX;                    // N*128 bf16, dinv-scaled
    unsigned short* agg0b = regX + (size_t)N * 128;  // N*128 bf16
    unsigned short* h2b   = regX;                    // N*256 (agg0b dead by then)
    unsigned short* h1b = (unsigned short*)carve((size_t)N * 256 * 2);  // dinv-scaled
    unsigned short* hwb = h1b;                       // N*128 (h1b dead by then)
    unsigned short* agg1b = (unsigned short*)carve((size_t)N * 256 * 2);

    // --- CSR build ---
    hipMemsetAsync(cnt, 0, (size_t)N * 4, stream);
    count_edges<<<(E / 4 + 255) / 256, 256, 0, stream>>>(col, E, cnt, rank);
    scan_reduce<<<NB, 256, 0, stream>>>(cnt, N, bsums);
    scan_finish<<<NB, 256, 0, stream>>>(cnt, N, bsums, NB, offs, dinv);
    fill_csr<<<(E / 4 + 255) / 256, 256, 0, stream>>>(row, col, rank, E, offs, esrc);

    // --- fused converts (needs dinv -> after scan_finish) ---
    {
        int n4 = N * 32;
        int tot = n4 + 32768 + 65536 + 32768;
        conv_fused<<<(tot + 255) / 256, 256, 0, stream>>>(
            (const float4*)x, (uint2*)xb, n4, dinv, W0, W1, W2, Wt0, Wt1, Wt2);
    }

    const int aggBlocks = (N + 3) / 4;  // 1 node/wave

    // L0: agg0 = Â xb ; h1 = relu(agg0 @ W0 + b0) * dinv
    aggregate_g<128, true, false><<<aggBlocks, 256, 0, stream>>>(
        (const unsigned*)xb, dinv, offs, esrc, nullptr, agg0b, N);
    gemm_blds<128, true, true, true><<<dim3(2, 391), 256, 0, stream>>>(
        agg0b, Wt0, b0, dinv, h1b, N, 256);
    // L1: agg1 = Â h1 ; h2 = relu(agg1 @ W1 + b1)
    aggregate_g<256, true, false><<<aggBlocks, 256, 0, stream>>>(
        (const unsigned*)h1b, dinv, offs, esrc, nullptr, agg1b, N);
    gemm_blds<256, true, true, false><<<dim3(2, 256), 256, 0, stream>>>(
        agg1b, Wt1, b1, nullptr, h2b, N, 256);
    // L2: hw = (h2 @ W2) * dinv ; out = Â hw + b2 (fp32)
    gemm_blds<256, false, false, true><<<dim3(1, 391), 256, 0, stream>>>(
        h2b, Wt2, nullptr, dinv, hwb, N, 128);
    aggregate_g<128, false, true><<<aggBlocks, 256, 0, stream>>>(
        (const unsigned*)hwb, dinv, offs, esrc, b2, d_out, N);
}

// Round 4
// 606.500 us; speedup vs baseline: 1.4605x; 1.0715x over previous
//
#include <hip/hip_runtime.h>

// ---------------------------------------------------------------------------
// GCN, bf16 pipeline, R10 = exact R6 (proven 592us) + GEMM grid rebalance.
//  - R7/R8/R9 falsified chunking AND producer pre-scaling: aggregation is
//    pinned at the ~3.8 TB/s random-line DRAM wall (FETCH/dur invariant across
//    all variants); every producer-side change regressed the non-agg portion.
//  - Revert: dense [N][D] tables, per-edge dinv fmaf aggregation, plain GEMM
//    epilogues (no SCALE), R6 conv_fused.
//  - NEW: grid balance only. gemm2 (1,391)->(1,782): 391 blocks on 256 CUs
//    left a 2x tail on doubled-up CUs. gemm1 (2,256)->(2,391): 782 tiles in
//    782 blocks, 2 tiles/block -> even 3 blocks/CU. Zero numeric change.
// ---------------------------------------------------------------------------

typedef __attribute__((ext_vector_type(8))) short bf16x8;
typedef __attribute__((ext_vector_type(4))) float f32x4;

__device__ __forceinline__ float bf_lo(unsigned u) {
    union { unsigned i; float f; } x; x.i = u << 16; return x.f;
}
__device__ __forceinline__ float bf_hi(unsigned u) {
    union { unsigned i; float f; } x; x.i = u & 0xFFFF0000u; return x.f;
}
__device__ __forceinline__ unsigned short f2bf(float f) {  // RNE
    union { float f; unsigned i; } x; x.f = f;
    unsigned r = x.i + 0x7FFFu + ((x.i >> 16) & 1u);
    return (unsigned short)(r >> 16);
}

// ----------------------------- CSR build -----------------------------------

__global__ __launch_bounds__(256) void count_edges(const int* __restrict__ col,
                                                   int E, int* __restrict__ cnt,
                                                   unsigned short* __restrict__ rank) {
    int base = (blockIdx.x * 256 + threadIdx.x) * 4;
    if (base + 3 < E) {
        int4 c = *(const int4*)(col + base);
        ushort4 r;
        r.x = (unsigned short)atomicAdd(&cnt[c.x], 1);
        r.y = (unsigned short)atomicAdd(&cnt[c.y], 1);
        r.z = (unsigned short)atomicAdd(&cnt[c.z], 1);
        r.w = (unsigned short)atomicAdd(&cnt[c.w], 1);
        *(ushort4*)(rank + base) = r;
    } else {
        for (int e = base; e < E; ++e)
            rank[e] = (unsigned short)atomicAdd(&cnt[col[e]], 1);
    }
}

__global__ __launch_bounds__(256) void scan_reduce(const int* __restrict__ cnt, int Nn,
                                                   int* __restrict__ blockSums) {
    __shared__ int s[256];
    int t = threadIdx.x;
    int base = blockIdx.x * 2048 + t * 8;
    int v = 0;
#pragma unroll
    for (int j = 0; j < 8; ++j) {
        int i = base + j;
        if (i < Nn) v += cnt[i];
    }
    s[t] = v;
    __syncthreads();
    for (int off = 128; off > 0; off >>= 1) {
        if (t < off) s[t] += s[t + off];
        __syncthreads();
    }
    if (t == 0) blockSums[blockIdx.x] = s[0];
}

__global__ __launch_bounds__(256) void scan_finish(const int* __restrict__ cnt, int Nn,
                                                   const int* __restrict__ blockSums, int nb,
                                                   int* __restrict__ offs,
                                                   float* __restrict__ dinv) {
    __shared__ int s[256];
    __shared__ int basePrefix;
    int t = threadIdx.x;
    if (t == 0) {
        int p = 0;
        for (int i = 0; i < (int)blockIdx.x; ++i) p += blockSums[i];
        basePrefix = p;
    }
    int base = blockIdx.x * 2048 + t * 8;
    int c[8];
    int sum = 0;
#pragma unroll
    for (int j = 0; j < 8; ++j) {
        int i = base + j;
        c[j] = (i < Nn) ? cnt[i] : 0;
        sum += c[j];
    }
    s[t] = sum;
    __syncthreads();
    for (int off = 1; off < 256; off <<= 1) {
        int v = (t >= off) ? s[t - off] : 0;
        __syncthreads();
        s[t] += v;
        __syncthreads();
    }
    int run = ((t > 0) ? s[t - 1] : 0) + basePrefix;
#pragma unroll
    for (int j = 0; j < 8; ++j) {
        int i = base + j;
        if (i < Nn) {
            offs[i] = run;
            dinv[i] = rsqrtf((float)(c[j] + 1));  // +1 self loop
            run += c[j];
        }
    }
    if (blockIdx.x == (unsigned)(nb - 1) && t == 255) offs[Nn] = basePrefix + s[255];
}

__global__ __launch_bounds__(256) void fill_csr(const int* __restrict__ row,
                                                const int* __restrict__ col,
                                                const unsigned short* __restrict__ rank,
                                                int E,
                                                const int* __restrict__ offs,
                                                int* __restrict__ esrc) {
    int base = (blockIdx.x * 256 + threadIdx.x) * 4;
    if (base + 3 < E) {
        int4 r = *(const int4*)(row + base);
        int4 c = *(const int4*)(col + base);
        ushort4 k = *(const ushort4*)(rank + base);
        esrc[offs[c.x] + k.x] = r.x;
        esrc[offs[c.y] + k.y] = r.y;
        esrc[offs[c.z] + k.z] = r.z;
        esrc[offs[c.w] + k.w] = r.w;
    } else {
        for (int e = base; e < E; ++e)
            esrc[offs[col[e]] + rank[e]] = row[e];
    }
}

// --------------------- fused converts (x + 3 weights) -----------------------

__global__ __launch_bounds__(256) void conv_fused(const float4* __restrict__ x4,
                                                  uint2* __restrict__ xb, int n4,
                                                  const float* __restrict__ W0,
                                                  const float* __restrict__ W1,
                                                  const float* __restrict__ W2,
                                                  unsigned short* __restrict__ Wt0,
                                                  unsigned short* __restrict__ Wt1,
                                                  unsigned short* __restrict__ Wt2) {
    int i = blockIdx.x * 256 + threadIdx.x;
    if (i < n4) {
        float4 v = x4[i];
        uint2 o;
        o.x = (unsigned)f2bf(v.x) | ((unsigned)f2bf(v.y) << 16);
        o.y = (unsigned)f2bf(v.z) | ((unsigned)f2bf(v.w) << 16);
        xb[i] = o;
        return;
    }
    int j = i - n4;
    if (j < 32768) {                        // Wt0[n*128+k] = W0[k*256+n]
        int n = j >> 7, k = j & 127;
        Wt0[j] = f2bf(W0[(size_t)k * 256 + n]);
    } else if (j < 32768 + 65536) {         // Wt1[n*256+k] = W1[k*256+n]
        int q = j - 32768;
        int n = q >> 8, k = q & 255;
        Wt1[q] = f2bf(W1[(size_t)k * 256 + n]);
    } else if (j < 32768 + 65536 + 32768) { // Wt2[n*256+k] = W2[k*128+n]
        int q = j - 98304;
        int n = q >> 8, k = q & 255;
        Wt2[q] = f2bf(W2[(size_t)k * 128 + n]);
    }
}

// ----------------------------- aggregation (R6, proven) ---------------------
template<int DFEAT, bool OUTBF, bool BIAS>
__global__ __launch_bounds__(256) void aggregate_g(const unsigned* __restrict__ hb,
                                                   const float* __restrict__ dinv,
                                                   const int* __restrict__ offs,
                                                   const int* __restrict__ esrc,
                                                   const float* __restrict__ bias,
                                                   void* __restrict__ out, int Nn) {
    constexpr int RW = DFEAT / 2;    // uints per row
    constexpr int G  = 512 / DFEAT;  // parallel edges (128->4, 256->2)
    constexpr int L  = 64 / G;       // lanes per row
    int node = (int)((blockIdx.x * 256u + threadIdx.x) >> 6);
    if (node >= Nn) return;
    int lane = threadIdx.x & 63;
    int grp = lane / L;
    int lid = lane % L;

    float acc[8];
    if (grp == 0) {  // self-loop term; folded by the reduction
        float dc0 = dinv[node];
        uint4 u = *(const uint4*)(hb + (size_t)node * RW + lid * 4);
        const unsigned* up = (const unsigned*)&u;
#pragma unroll
        for (int q = 0; q < 4; ++q) {
            acc[2 * q]     = dc0 * bf_lo(up[q]);
            acc[2 * q + 1] = dc0 * bf_hi(up[q]);
        }
    } else {
#pragma unroll
        for (int q = 0; q < 8; ++q) acc[q] = 0.f;
    }

    int e0 = offs[node], e1 = offs[node + 1];
    int k = e0 + grp;
    while (k + 3 * G < e1) {
        int s0 = esrc[k], s1 = esrc[k + G], s2 = esrc[k + 2 * G], s3 = esrc[k + 3 * G];
        float d0 = dinv[s0], d1 = dinv[s1], d2 = dinv[s2], d3 = dinv[s3];
        uint4 u0 = *(const uint4*)(hb + (size_t)s0 * RW + lid * 4);
        uint4 u1 = *(const uint4*)(hb + (size_t)s1 * RW + lid * 4);
        uint4 u2 = *(const uint4*)(hb + (size_t)s2 * RW + lid * 4);
        uint4 u3 = *(const uint4*)(hb + (size_t)s3 * RW + lid * 4);
        const unsigned* u0p = (const unsigned*)&u0;
        const unsigned* u1p = (const unsigned*)&u1;
        const unsigned* u2p = (const unsigned*)&u2;
        const unsigned* u3p = (const unsigned*)&u3;
#pragma unroll
        for (int q = 0; q < 4; ++q) {
            acc[2 * q]     = fmaf(d0, bf_lo(u0p[q]), acc[2 * q]);
            acc[2 * q + 1] = fmaf(d0, bf_hi(u0p[q]), acc[2 * q + 1]);
            acc[2 * q]     = fmaf(d1, bf_lo(u1p[q]), acc[2 * q]);
            acc[2 * q + 1] = fmaf(d1, bf_hi(u1p[q]), acc[2 * q + 1]);
            acc[2 * q]     = fmaf(d2, bf_lo(u2p[q]), acc[2 * q]);
            acc[2 * q + 1] = fmaf(d2, bf_hi(u2p[q]), acc[2 * q + 1]);
            acc[2 * q]     = fmaf(d3, bf_lo(u3p[q]), acc[2 * q]);
            acc[2 * q + 1] = fmaf(d3, bf_hi(u3p[q]), acc[2 * q + 1]);
        }
        k += 4 * G;
    }
    while (k < e1) {
        int s0 = esrc[k];
        float d0 = dinv[s0];
        uint4 u0 = *(const uint4*)(hb + (size_t)s0 * RW + lid * 4);
        const unsigned* u0p = (const unsigned*)&u0;
#pragma unroll
        for (int q = 0; q < 4; ++q) {
            acc[2 * q]     = fmaf(d0, bf_lo(u0p[q]), acc[2 * q]);
            acc[2 * q + 1] = fmaf(d0, bf_hi(u0p[q]), acc[2 * q + 1]);
        }
        k += G;
    }

#pragma unroll
    for (int q = 0; q < 8; ++q) {
        if (G == 4) {
            acc[q] += __shfl_xor(acc[q], 16, 64);
            acc[q] += __shfl_xor(acc[q], 32, 64);
        } else {
            acc[q] += __shfl_xor(acc[q], 32, 64);
        }
    }

    float dc = dinv[node];
    if (grp == 0) {
        if (OUTBF) {
            uint4 o;
            unsigned* op = (unsigned*)&o;
#pragma unroll
            for (int q = 0; q < 4; ++q) {
                float v0 = acc[2 * q] * dc;
                float v1 = acc[2 * q + 1] * dc;
                op[q] = (unsigned)f2bf(v0) | ((unsigned)f2bf(v1) << 16);
            }
            *(uint4*)((unsigned*)out + (size_t)node * RW + lid * 4) = o;
        } else {
            float4 o0, o1;
            float* o0p = (float*)&o0;
            float* o1p = (float*)&o1;
#pragma unroll
            for (int q = 0; q < 4; ++q) {
                float b0v = BIAS ? bias[lid * 8 + 2 * q] : 0.f;
                float b1v = BIAS ? bias[lid * 8 + 2 * q + 1] : 0.f;
                float v0 = acc[2 * q] * dc + b0v;
                float v1 = acc[2 * q + 1] * dc + b1v;
                if (q < 2) { o0p[2 * q] = v0; o0p[2 * q + 1] = v1; }
                else       { o1p[2 * (q - 2)] = v0; o1p[2 * (q - 2) + 1] = v1; }
            }
            float* ob = (float*)out + (size_t)node * DFEAT + lid * 8;
            *(float4*)ob = o0;
            *(float4*)(ob + 4) = o1;
        }
    }
}

// --------------------- MFMA GEMM: B panel in LDS, persistent M --------------
// C[Nrows,Dout] = A[Nrows,K]@W (+bias)(+relu); A,Wt,C bf16; Wt=[Dout][K].
// Block: 4 waves (2x2), 128x128 tile, loops M-tiles (stride gridDim.y*128).
// B panel (128 cols x K) loaded into LDS ONCE (rows padded +8 halves so frag
// ds_read_b128 is 2-way bank-aliased = free), then the K-loop has NO barriers:
// A frags stream global->VGPR (16 rows x 64B dense lines), B frags from LDS.
// Frag maps (verified R3-R6): A/B: idx=lane&15, k=(lane>>4)*8+j;
//                             C: col=lane&15, row=(lane>>4)*4+reg.
template<int K, bool RELU, bool BIAS>
__global__ __launch_bounds__(256) void gemm_blds(const unsigned short* __restrict__ A,
                                                 const unsigned short* __restrict__ Wt,
                                                 const float* __restrict__ bias,
                                                 unsigned short* __restrict__ C,
                                                 int Nrows, int Dout) {
    constexpr int KP = K + 8;  // padded row stride (halves)
    __shared__ __align__(16) unsigned short Bsh[128 * KP];
    int t = threadIdx.x;
    int n0 = blockIdx.x << 7;

    // One-time B panel load (Dout is a multiple of 128 -> no tail).
    constexpr int CHUNKS = 128 * (K / 8);
    for (int c = t; c < CHUNKS; c += 256) {
        int rown = c / (K / 8);
        int kc = c - rown * (K / 8);
        *(bf16x8*)&Bsh[rown * KP + kc * 8] =
            *(const bf16x8*)&Wt[(size_t)(n0 + rown) * K + kc * 8];
    }
    __syncthreads();

    int w = t >> 6, lane = t & 63;
    int lrow = lane & 15, lkq = lane >> 4;
    int wr = w >> 1, wc = w & 1;
    const unsigned short* bbase = &Bsh[(wc * 64 + lrow) * KP + lkq * 8];

    for (int m0 = blockIdx.y * 128; m0 < Nrows; m0 += gridDim.y * 128) {
        f32x4 acc[4][4];
#pragma unroll
        for (int i = 0; i < 4; ++i)
#pragma unroll
            for (int j = 0; j < 4; ++j) acc[i][j] = (f32x4){0.f, 0.f, 0.f, 0.f};

        const unsigned short* ap[4];
#pragma unroll
        for (int i = 0; i < 4; ++i) {
            int r = min(m0 + wr * 64 + i * 16 + lrow, Nrows - 1);
            ap[i] = A + (size_t)r * K + lkq * 8;
        }

        bf16x8 a0[4], a1[4];
#pragma unroll
        for (int i = 0; i < 4; ++i) a0[i] = *(const bf16x8*)(ap[i]);
#pragma unroll
        for (int s = 0; s < K / 32; ++s) {
            bf16x8* cur = (s & 1) ? a1 : a0;
            bf16x8* nxt = (s & 1) ? a0 : a1;
            if (s + 1 < K / 32) {
#pragma unroll
                for (int i = 0; i < 4; ++i)
                    nxt[i] = *(const bf16x8*)(ap[i] + (s + 1) * 32);
            }
            bf16x8 bfr[4];
#pragma unroll
            for (int j = 0; j < 4; ++j)
                bfr[j] = *(const bf16x8*)(bbase + j * 16 * KP + s * 32);
#pragma unroll
            for (int i = 0; i < 4; ++i)
#pragma unroll
                for (int j = 0; j < 4; ++j)
                    acc[i][j] = __builtin_amdgcn_mfma_f32_16x16x32_bf16(
                        cur[i], bfr[j], acc[i][j], 0, 0, 0);
        }

#pragma unroll
        for (int j = 0; j < 4; ++j) {
            int colc = n0 + ((wc * 4 + j) << 4) + lrow;
            float bj = BIAS ? bias[colc] : 0.f;
#pragma unroll
            for (int i = 0; i < 4; ++i) {
                int rb = m0 + wr * 64 + i * 16 + (lkq << 2);
                f32x4 c = acc[i][j];
#pragma unroll
                for (int r = 0; r < 4; ++r) {
                    int rowc = rb + r;
                    if (rowc < Nrows) {
                        float v = c[r] + bj;
                        if (RELU) v = fmaxf(v, 0.f);
                        C[(size_t)rowc * Dout + colc] = f2bf(v);
                    }
                }
            }
        }
    }
}

// ----------------------------- launch --------------------------------------

extern "C" void kernel_launch(void* const* d_in, const int* in_sizes, int n_in,
                              void* d_out, int out_size, void* d_ws, size_t ws_size,
                              hipStream_t stream) {
    const float* x  = (const float*)d_in[0];
    const int*   ei = (const int*)d_in[1];
    const float* W0 = (const float*)d_in[4];
    const float* b0 = (const float*)d_in[5];
    const float* W1 = (const float*)d_in[6];
    const float* b1 = (const float*)d_in[7];
    const float* W2 = (const float*)d_in[8];
    const float* b2 = (const float*)d_in[9];

    const int N = in_sizes[0] / 128;
    const int E = in_sizes[1] / 2;
    const int* row = ei;       // sources
    const int* col = ei + E;   // destinations

    char* wp = (char*)d_ws;
    auto carve = [&](size_t bytes) {
        void* p = (void*)wp;
        wp += (bytes + 255) & ~(size_t)255;
        return p;
    };
    const int NB = (N + 2047) / 2048;
    int*   cnt    = (int*)carve((size_t)N * 4);
    int*   offs   = (int*)carve((size_t)(N + 1) * 4);
    unsigned short* rank = (unsigned short*)carve((size_t)E * 2);
    int*   esrc   = (int*)carve((size_t)E * 4);
    float* dinv   = (float*)carve((size_t)N * 4);
    int*   bsums  = (int*)carve((size_t)NB * 4);
    unsigned short* Wt0 = (unsigned short*)carve((size_t)256 * 128 * 2);
    unsigned short* Wt1 = (unsigned short*)carve((size_t)256 * 256 * 2);
    unsigned short* Wt2 = (unsigned short*)carve((size_t)128 * 256 * 2);
    unsigned short* regX = (unsigned short*)carve((size_t)N * 256 * 2);
    unsigned short* xb    = regX;                    // N*128 bf16
    unsigned short* agg0b = regX + (size_t)N * 128;  // N*128 bf16
    unsigned short* h2b   = regX;                    // N*256 (agg0b dead by then)
    unsigned short* h1b = (unsigned short*)carve((size_t)N * 256 * 2);
    unsigned short* hwb = h1b;                       // N*128 (h1b dead by then)
    unsigned short* agg1b = (unsigned short*)carve((size_t)N * 256 * 2);

    // --- CSR build ---
    hipMemsetAsync(cnt, 0, (size_t)N * 4, stream);
    count_edges<<<(E / 4 + 255) / 256, 256, 0, stream>>>(col, E, cnt, rank);
    scan_reduce<<<NB, 256, 0, stream>>>(cnt, N, bsums);
    scan_finish<<<NB, 256, 0, stream>>>(cnt, N, bsums, NB, offs, dinv);
    fill_csr<<<(E / 4 + 255) / 256, 256, 0, stream>>>(row, col, rank, E, offs, esrc);

    // --- fused converts ---
    {
        int n4 = N * 128 / 4;
        int tot = n4 + 32768 + 65536 + 32768;
        conv_fused<<<(tot + 255) / 256, 256, 0, stream>>>(
            (const float4*)x, (uint2*)xb, n4, W0, W1, W2, Wt0, Wt1, Wt2);
    }

    const int aggBlocks = (N + 3) / 4;  // 1 node/wave

    // GEMM grids: x = Dout/128 col-panels; y = persistent M-stride.
    // 782 M-tiles total (N=100K). Balance: blocks == tiles or tiles/2 so no
    // CU carries a 2x-long block while others idle.
    // gemm0: K=128, 34KB LDS: (2,391) -> 782 blocks, 2 tiles each.  (R6)
    // gemm1: K=256, 68KB LDS: (2,391) -> 782 blocks, 2 tiles each.  (was 256)
    // gemm2: K=256, Dout=128: (1,782) -> 782 blocks, 1 tile each.   (was 391)

    // L0: agg0 = Â xb ; h1 = relu(agg0 @ W0 + b0)
    aggregate_g<128, true, false><<<aggBlocks, 256, 0, stream>>>(
        (const unsigned*)xb, dinv, offs, esrc, nullptr, agg0b, N);
    gemm_blds<128, true, true><<<dim3(2, 391), 256, 0, stream>>>(
        agg0b, Wt0, b0, h1b, N, 256);
    // L1: agg1 = Â h1 ; h2 = relu(agg1 @ W1 + b1)
    aggregate_g<256, true, false><<<aggBlocks, 256, 0, stream>>>(
        (const unsigned*)h1b, dinv, offs, esrc, nullptr, agg1b, N);
    gemm_blds<256, true, true><<<dim3(2, 391), 256, 0, stream>>>(
        agg1b, Wt1, b1, h2b, N, 256);
    // L2: hw = h2 @ W2 ; out = Â hw + b2 (fp32)
    gemm_blds<256, false, false><<<dim3(1, 782), 256, 0, stream>>>(
        h2b, Wt2, nullptr, hwb, N, 128);
    aggregate_g<128, false, true><<<aggBlocks, 256, 0, stream>>>(
        (const unsigned*)hwb, dinv, offs, esrc, b2, d_out, N);
}

// Round 5
// 594.046 us; speedup vs baseline: 1.4911x; 1.0210x over previous
//
#include <hip/hip_runtime.h>

// ---------------------------------------------------------------------------
// GCN, bf16 pipeline, R11 = exact R6 (proven 592us) + 3-deep GEMM A-prefetch.
//  - R7-R10 mapped the aggregation pareto: dense dest-major gather is pinned
//    at the ~3.35 TB/s beyond-L2 random-64B wall (FETCH/dur invariant across
//    chunked/L2-resident/pre-scaled variants). R6 aggregation untouched.
//  - R10 falsified the grid rebalance: (2,256)/(1,391) were already optimal
//    for the 2-blocks/CU LDS cap (exact residency, no second round). Reverted.
//  - NEW: gemm_blds K-loop triple-buffers A (prefetch s+2): at 8 waves/CU
//    (K=256, 68KB LDS) the 1-step MFMA shadow (~160cy/SIMD) < A-line latency
//    (~200-500cy); 2-step lookahead covers it. +16 VGPR, fully unrolled,
//    no numeric/layout change.
// ---------------------------------------------------------------------------

typedef __attribute__((ext_vector_type(8))) short bf16x8;
typedef __attribute__((ext_vector_type(4))) float f32x4;

__device__ __forceinline__ float bf_lo(unsigned u) {
    union { unsigned i; float f; } x; x.i = u << 16; return x.f;
}
__device__ __forceinline__ float bf_hi(unsigned u) {
    union { unsigned i; float f; } x; x.i = u & 0xFFFF0000u; return x.f;
}
__device__ __forceinline__ unsigned short f2bf(float f) {  // RNE
    union { float f; unsigned i; } x; x.f = f;
    unsigned r = x.i + 0x7FFFu + ((x.i >> 16) & 1u);
    return (unsigned short)(r >> 16);
}

// ----------------------------- CSR build -----------------------------------

__global__ __launch_bounds__(256) void count_edges(const int* __restrict__ col,
                                                   int E, int* __restrict__ cnt,
                                                   unsigned short* __restrict__ rank) {
    int base = (blockIdx.x * 256 + threadIdx.x) * 4;
    if (base + 3 < E) {
        int4 c = *(const int4*)(col + base);
        ushort4 r;
        r.x = (unsigned short)atomicAdd(&cnt[c.x], 1);
        r.y = (unsigned short)atomicAdd(&cnt[c.y], 1);
        r.z = (unsigned short)atomicAdd(&cnt[c.z], 1);
        r.w = (unsigned short)atomicAdd(&cnt[c.w], 1);
        *(ushort4*)(rank + base) = r;
    } else {
        for (int e = base; e < E; ++e)
            rank[e] = (unsigned short)atomicAdd(&cnt[col[e]], 1);
    }
}

__global__ __launch_bounds__(256) void scan_reduce(const int* __restrict__ cnt, int Nn,
                                                   int* __restrict__ blockSums) {
    __shared__ int s[256];
    int t = threadIdx.x;
    int base = blockIdx.x * 2048 + t * 8;
    int v = 0;
#pragma unroll
    for (int j = 0; j < 8; ++j) {
        int i = base + j;
        if (i < Nn) v += cnt[i];
    }
    s[t] = v;
    __syncthreads();
    for (int off = 128; off > 0; off >>= 1) {
        if (t < off) s[t] += s[t + off];
        __syncthreads();
    }
    if (t == 0) blockSums[blockIdx.x] = s[0];
}

__global__ __launch_bounds__(256) void scan_finish(const int* __restrict__ cnt, int Nn,
                                                   const int* __restrict__ blockSums, int nb,
                                                   int* __restrict__ offs,
                                                   float* __restrict__ dinv) {
    __shared__ int s[256];
    __shared__ int basePrefix;
    int t = threadIdx.x;
    if (t == 0) {
        int p = 0;
        for (int i = 0; i < (int)blockIdx.x; ++i) p += blockSums[i];
        basePrefix = p;
    }
    int base = blockIdx.x * 2048 + t * 8;
    int c[8];
    int sum = 0;
#pragma unroll
    for (int j = 0; j < 8; ++j) {
        int i = base + j;
        c[j] = (i < Nn) ? cnt[i] : 0;
        sum += c[j];
    }
    s[t] = sum;
    __syncthreads();
    for (int off = 1; off < 256; off <<= 1) {
        int v = (t >= off) ? s[t - off] : 0;
        __syncthreads();
        s[t] += v;
        __syncthreads();
    }
    int run = ((t > 0) ? s[t - 1] : 0) + basePrefix;
#pragma unroll
    for (int j = 0; j < 8; ++j) {
        int i = base + j;
        if (i < Nn) {
            offs[i] = run;
            dinv[i] = rsqrtf((float)(c[j] + 1));  // +1 self loop
            run += c[j];
        }
    }
    if (blockIdx.x == (unsigned)(nb - 1) && t == 255) offs[Nn] = basePrefix + s[255];
}

__global__ __launch_bounds__(256) void fill_csr(const int* __restrict__ row,
                                                const int* __restrict__ col,
                                                const unsigned short* __restrict__ rank,
                                                int E,
                                                const int* __restrict__ offs,
                                                int* __restrict__ esrc) {
    int base = (blockIdx.x * 256 + threadIdx.x) * 4;
    if (base + 3 < E) {
        int4 r = *(const int4*)(row + base);
        int4 c = *(const int4*)(col + base);
        ushort4 k = *(const ushort4*)(rank + base);
        esrc[offs[c.x] + k.x] = r.x;
        esrc[offs[c.y] + k.y] = r.y;
        esrc[offs[c.z] + k.z] = r.z;
        esrc[offs[c.w] + k.w] = r.w;
    } else {
        for (int e = base; e < E; ++e)
            esrc[offs[col[e]] + rank[e]] = row[e];
    }
}

// --------------------- fused converts (x + 3 weights) -----------------------

__global__ __launch_bounds__(256) void conv_fused(const float4* __restrict__ x4,
                                                  uint2* __restrict__ xb, int n4,
                                                  const float* __restrict__ W0,
                                                  const float* __restrict__ W1,
                                                  const float* __restrict__ W2,
                                                  unsigned short* __restrict__ Wt0,
                                                  unsigned short* __restrict__ Wt1,
                                                  unsigned short* __restrict__ Wt2) {
    int i = blockIdx.x * 256 + threadIdx.x;
    if (i < n4) {
        float4 v = x4[i];
        uint2 o;
        o.x = (unsigned)f2bf(v.x) | ((unsigned)f2bf(v.y) << 16);
        o.y = (unsigned)f2bf(v.z) | ((unsigned)f2bf(v.w) << 16);
        xb[i] = o;
        return;
    }
    int j = i - n4;
    if (j < 32768) {                        // Wt0[n*128+k] = W0[k*256+n]
        int n = j >> 7, k = j & 127;
        Wt0[j] = f2bf(W0[(size_t)k * 256 + n]);
    } else if (j < 32768 + 65536) {         // Wt1[n*256+k] = W1[k*256+n]
        int q = j - 32768;
        int n = q >> 8, k = q & 255;
        Wt1[q] = f2bf(W1[(size_t)k * 256 + n]);
    } else if (j < 32768 + 65536 + 32768) { // Wt2[n*256+k] = W2[k*128+n]
        int q = j - 98304;
        int n = q >> 8, k = q & 255;
        Wt2[q] = f2bf(W2[(size_t)k * 128 + n]);
    }
}

// ----------------------------- aggregation (R6, proven) ---------------------
template<int DFEAT, bool OUTBF, bool BIAS>
__global__ __launch_bounds__(256) void aggregate_g(const unsigned* __restrict__ hb,
                                                   const float* __restrict__ dinv,
                                                   const int* __restrict__ offs,
                                                   const int* __restrict__ esrc,
                                                   const float* __restrict__ bias,
                                                   void* __restrict__ out, int Nn) {
    constexpr int RW = DFEAT / 2;    // uints per row
    constexpr int G  = 512 / DFEAT;  // parallel edges (128->4, 256->2)
    constexpr int L  = 64 / G;       // lanes per row
    int node = (int)((blockIdx.x * 256u + threadIdx.x) >> 6);
    if (node >= Nn) return;
    int lane = threadIdx.x & 63;
    int grp = lane / L;
    int lid = lane % L;

    float acc[8];
    if (grp == 0) {  // self-loop term; folded by the reduction
        float dc0 = dinv[node];
        uint4 u = *(const uint4*)(hb + (size_t)node * RW + lid * 4);
        const unsigned* up = (const unsigned*)&u;
#pragma unroll
        for (int q = 0; q < 4; ++q) {
            acc[2 * q]     = dc0 * bf_lo(up[q]);
            acc[2 * q + 1] = dc0 * bf_hi(up[q]);
        }
    } else {
#pragma unroll
        for (int q = 0; q < 8; ++q) acc[q] = 0.f;
    }

    int e0 = offs[node], e1 = offs[node + 1];
    int k = e0 + grp;
    while (k + 3 * G < e1) {
        int s0 = esrc[k], s1 = esrc[k + G], s2 = esrc[k + 2 * G], s3 = esrc[k + 3 * G];
        float d0 = dinv[s0], d1 = dinv[s1], d2 = dinv[s2], d3 = dinv[s3];
        uint4 u0 = *(const uint4*)(hb + (size_t)s0 * RW + lid * 4);
        uint4 u1 = *(const uint4*)(hb + (size_t)s1 * RW + lid * 4);
        uint4 u2 = *(const uint4*)(hb + (size_t)s2 * RW + lid * 4);
        uint4 u3 = *(const uint4*)(hb + (size_t)s3 * RW + lid * 4);
        const unsigned* u0p = (const unsigned*)&u0;
        const unsigned* u1p = (const unsigned*)&u1;
        const unsigned* u2p = (const unsigned*)&u2;
        const unsigned* u3p = (const unsigned*)&u3;
#pragma unroll
        for (int q = 0; q < 4; ++q) {
            acc[2 * q]     = fmaf(d0, bf_lo(u0p[q]), acc[2 * q]);
            acc[2 * q + 1] = fmaf(d0, bf_hi(u0p[q]), acc[2 * q + 1]);
            acc[2 * q]     = fmaf(d1, bf_lo(u1p[q]), acc[2 * q]);
            acc[2 * q + 1] = fmaf(d1, bf_hi(u1p[q]), acc[2 * q + 1]);
            acc[2 * q]     = fmaf(d2, bf_lo(u2p[q]), acc[2 * q]);
            acc[2 * q + 1] = fmaf(d2, bf_hi(u2p[q]), acc[2 * q + 1]);
            acc[2 * q]     = fmaf(d3, bf_lo(u3p[q]), acc[2 * q]);
            acc[2 * q + 1] = fmaf(d3, bf_hi(u3p[q]), acc[2 * q + 1]);
        }
        k += 4 * G;
    }
    while (k < e1) {
        int s0 = esrc[k];
        float d0 = dinv[s0];
        uint4 u0 = *(const uint4*)(hb + (size_t)s0 * RW + lid * 4);
        const unsigned* u0p = (const unsigned*)&u0;
#pragma unroll
        for (int q = 0; q < 4; ++q) {
            acc[2 * q]     = fmaf(d0, bf_lo(u0p[q]), acc[2 * q]);
            acc[2 * q + 1] = fmaf(d0, bf_hi(u0p[q]), acc[2 * q + 1]);
        }
        k += G;
    }

#pragma unroll
    for (int q = 0; q < 8; ++q) {
        if (G == 4) {
            acc[q] += __shfl_xor(acc[q], 16, 64);
            acc[q] += __shfl_xor(acc[q], 32, 64);
        } else {
            acc[q] += __shfl_xor(acc[q], 32, 64);
        }
    }

    float dc = dinv[node];
    if (grp == 0) {
        if (OUTBF) {
            uint4 o;
            unsigned* op = (unsigned*)&o;
#pragma unroll
            for (int q = 0; q < 4; ++q) {
                float v0 = acc[2 * q] * dc;
                float v1 = acc[2 * q + 1] * dc;
                op[q] = (unsigned)f2bf(v0) | ((unsigned)f2bf(v1) << 16);
            }
            *(uint4*)((unsigned*)out + (size_t)node * RW + lid * 4) = o;
        } else {
            float4 o0, o1;
            float* o0p = (float*)&o0;
            float* o1p = (float*)&o1;
#pragma unroll
            for (int q = 0; q < 4; ++q) {
                float b0v = BIAS ? bias[lid * 8 + 2 * q] : 0.f;
                float b1v = BIAS ? bias[lid * 8 + 2 * q + 1] : 0.f;
                float v0 = acc[2 * q] * dc + b0v;
                float v1 = acc[2 * q + 1] * dc + b1v;
                if (q < 2) { o0p[2 * q] = v0; o0p[2 * q + 1] = v1; }
                else       { o1p[2 * (q - 2)] = v0; o1p[2 * (q - 2) + 1] = v1; }
            }
            float* ob = (float*)out + (size_t)node * DFEAT + lid * 8;
            *(float4*)ob = o0;
            *(float4*)(ob + 4) = o1;
        }
    }
}

// --------------------- MFMA GEMM: B panel in LDS, persistent M --------------
// C[Nrows,Dout] = A[Nrows,K]@W (+bias)(+relu); A,Wt,C bf16; Wt=[Dout][K].
// Block: 4 waves (2x2), 128x128 tile, loops M-tiles (stride gridDim.y*128).
// B panel (128 cols x K) loaded into LDS ONCE (rows padded +8 halves so frag
// ds_read_b128 is 2-way bank-aliased = free), then the K-loop has NO barriers:
// A frags stream global->VGPR (16 rows x 64B dense lines), B frags from LDS.
// A is TRIPLE-buffered (prefetch s+2): at 2 blocks/CU (K=256) the 1-step MFMA
// shadow doesn't cover A-line latency; 2-step lookahead does.
// Frag maps (verified R3-R6): A/B: idx=lane&15, k=(lane>>4)*8+j;
//                             C: col=lane&15, row=(lane>>4)*4+reg.
template<int K, bool RELU, bool BIAS>
__global__ __launch_bounds__(256) void gemm_blds(const unsigned short* __restrict__ A,
                                                 const unsigned short* __restrict__ Wt,
                                                 const float* __restrict__ bias,
                                                 unsigned short* __restrict__ C,
                                                 int Nrows, int Dout) {
    constexpr int KP = K + 8;  // padded row stride (halves)
    __shared__ __align__(16) unsigned short Bsh[128 * KP];
    int t = threadIdx.x;
    int n0 = blockIdx.x << 7;

    // One-time B panel load (Dout is a multiple of 128 -> no tail).
    constexpr int CHUNKS = 128 * (K / 8);
    for (int c = t; c < CHUNKS; c += 256) {
        int rown = c / (K / 8);
        int kc = c - rown * (K / 8);
        *(bf16x8*)&Bsh[rown * KP + kc * 8] =
            *(const bf16x8*)&Wt[(size_t)(n0 + rown) * K + kc * 8];
    }
    __syncthreads();

    int w = t >> 6, lane = t & 63;
    int lrow = lane & 15, lkq = lane >> 4;
    int wr = w >> 1, wc = w & 1;
    const unsigned short* bbase = &Bsh[(wc * 64 + lrow) * KP + lkq * 8];

    constexpr int NS = K / 32;  // K-steps (4 or 8)

    for (int m0 = blockIdx.y * 128; m0 < Nrows; m0 += gridDim.y * 128) {
        f32x4 acc[4][4];
#pragma unroll
        for (int i = 0; i < 4; ++i)
#pragma unroll
            for (int j = 0; j < 4; ++j) acc[i][j] = (f32x4){0.f, 0.f, 0.f, 0.f};

        const unsigned short* ap[4];
#pragma unroll
        for (int i = 0; i < 4; ++i) {
            int r = min(m0 + wr * 64 + i * 16 + lrow, Nrows - 1);
            ap[i] = A + (size_t)r * K + lkq * 8;
        }

        bf16x8 abuf[3][4];
#pragma unroll
        for (int i = 0; i < 4; ++i) abuf[0][i] = *(const bf16x8*)(ap[i]);
#pragma unroll
        for (int i = 0; i < 4; ++i) abuf[1][i] = *(const bf16x8*)(ap[i] + 32);

#pragma unroll
        for (int s = 0; s < NS; ++s) {
            if (s + 2 < NS) {
#pragma unroll
                for (int i = 0; i < 4; ++i)
                    abuf[(s + 2) % 3][i] = *(const bf16x8*)(ap[i] + (s + 2) * 32);
            }
            bf16x8 bfr[4];
#pragma unroll
            for (int j = 0; j < 4; ++j)
                bfr[j] = *(const bf16x8*)(bbase + j * 16 * KP + s * 32);
#pragma unroll
            for (int i = 0; i < 4; ++i)
#pragma unroll
                for (int j = 0; j < 4; ++j)
                    acc[i][j] = __builtin_amdgcn_mfma_f32_16x16x32_bf16(
                        abuf[s % 3][i], bfr[j], acc[i][j], 0, 0, 0);
        }

#pragma unroll
        for (int j = 0; j < 4; ++j) {
            int colc = n0 + ((wc * 4 + j) << 4) + lrow;
            float bj = BIAS ? bias[colc] : 0.f;
#pragma unroll
            for (int i = 0; i < 4; ++i) {
                int rb = m0 + wr * 64 + i * 16 + (lkq << 2);
                f32x4 c = acc[i][j];
#pragma unroll
                for (int r = 0; r < 4; ++r) {
                    int rowc = rb + r;
                    if (rowc < Nrows) {
                        float v = c[r] + bj;
                        if (RELU) v = fmaxf(v, 0.f);
                        C[(size_t)rowc * Dout + colc] = f2bf(v);
                    }
                }
            }
        }
    }
}

// ----------------------------- launch --------------------------------------

extern "C" void kernel_launch(void* const* d_in, const int* in_sizes, int n_in,
                              void* d_out, int out_size, void* d_ws, size_t ws_size,
                              hipStream_t stream) {
    const float* x  = (const float*)d_in[0];
    const int*   ei = (const int*)d_in[1];
    const float* W0 = (const float*)d_in[4];
    const float* b0 = (const float*)d_in[5];
    const float* W1 = (const float*)d_in[6];
    const float* b1 = (const float*)d_in[7];
    const float* W2 = (const float*)d_in[8];
    const float* b2 = (const float*)d_in[9];

    const int N = in_sizes[0] / 128;
    const int E = in_sizes[1] / 2;
    const int* row = ei;       // sources
    const int* col = ei + E;   // destinations

    char* wp = (char*)d_ws;
    auto carve = [&](size_t bytes) {
        void* p = (void*)wp;
        wp += (bytes + 255) & ~(size_t)255;
        return p;
    };
    const int NB = (N + 2047) / 2048;
    int*   cnt    = (int*)carve((size_t)N * 4);
    int*   offs   = (int*)carve((size_t)(N + 1) * 4);
    unsigned short* rank = (unsigned short*)carve((size_t)E * 2);
    int*   esrc   = (int*)carve((size_t)E * 4);
    float* dinv   = (float*)carve((size_t)N * 4);
    int*   bsums  = (int*)carve((size_t)NB * 4);
    unsigned short* Wt0 = (unsigned short*)carve((size_t)256 * 128 * 2);
    unsigned short* Wt1 = (unsigned short*)carve((size_t)256 * 256 * 2);
    unsigned short* Wt2 = (unsigned short*)carve((size_t)128 * 256 * 2);
    unsigned short* regX = (unsigned short*)carve((size_t)N * 256 * 2);
    unsigned short* xb    = regX;                    // N*128 bf16
    unsigned short* agg0b = regX + (size_t)N * 128;  // N*128 bf16
    unsigned short* h2b   = regX;                    // N*256 (agg0b dead by then)
    unsigned short* h1b = (unsigned short*)carve((size_t)N * 256 * 2);
    unsigned short* hwb = h1b;                       // N*128 (h1b dead by then)
    unsigned short* agg1b = (unsigned short*)carve((size_t)N * 256 * 2);

    // --- CSR build ---
    hipMemsetAsync(cnt, 0, (size_t)N * 4, stream);
    count_edges<<<(E / 4 + 255) / 256, 256, 0, stream>>>(col, E, cnt, rank);
    scan_reduce<<<NB, 256, 0, stream>>>(cnt, N, bsums);
    scan_finish<<<NB, 256, 0, stream>>>(cnt, N, bsums, NB, offs, dinv);
    fill_csr<<<(E / 4 + 255) / 256, 256, 0, stream>>>(row, col, rank, E, offs, esrc);

    // --- fused converts ---
    {
        int n4 = N * 128 / 4;
        int tot = n4 + 32768 + 65536 + 32768;
        conv_fused<<<(tot + 255) / 256, 256, 0, stream>>>(
            (const float4*)x, (uint2*)xb, n4, W0, W1, W2, Wt0, Wt1, Wt2);
    }

    const int aggBlocks = (N + 3) / 4;  // 1 node/wave

    // GEMM grids (R6, proven optimal for the LDS-capped occupancy):
    // gemm0: K=128 -> 34KB LDS (4 blk/CU): (2,391) = 782 blocks, 2 tiles each.
    // gemm1: K=256 -> 68KB LDS (2 blk/CU): (2,256) = 512 blocks = exact
    //        residency, 3-4 tiles each, zero launch tail.
    // gemm2: K=256, Dout=128: (1,391) -> all resident, 2 tiles each.

    // L0: agg0 = Â xb ; h1 = relu(agg0 @ W0 + b0)
    aggregate_g<128, true, false><<<aggBlocks, 256, 0, stream>>>(
        (const unsigned*)xb, dinv, offs, esrc, nullptr, agg0b, N);
    gemm_blds<128, true, true><<<dim3(2, 391), 256, 0, stream>>>(
        agg0b, Wt0, b0, h1b, N, 256);
    // L1: agg1 = Â h1 ; h2 = relu(agg1 @ W1 + b1)
    aggregate_g<256, true, false><<<aggBlocks, 256, 0, stream>>>(
        (const unsigned*)h1b, dinv, offs, esrc, nullptr, agg1b, N);
    gemm_blds<256, true, true><<<dim3(2, 256), 256, 0, stream>>>(
        agg1b, Wt1, b1, h2b, N, 256);
    // L2: hw = h2 @ W2 ; out = Â hw + b2 (fp32)
    gemm_blds<256, false, false><<<dim3(1, 391), 256, 0, stream>>>(
        h2b, Wt2, nullptr, hwb, N, 128);
    aggregate_g<128, false, true><<<aggBlocks, 256, 0, stream>>>(
        (const unsigned*)hwb, dinv, offs, esrc, b2, d_out, N);
}